// Round 7
// baseline (1122.282 us; speedup 1.0000x reference)
//
#include <hip/hip_runtime.h>
#include <hip/hip_bf16.h>
#include <stdint.h>
#include <stddef.h>

using bf16 = __hip_bfloat16;
typedef __attribute__((ext_vector_type(8))) short short8;   // 8 bf16 (4 VGPRs)
typedef __attribute__((ext_vector_type(4))) float f32x4;
typedef __attribute__((ext_vector_type(2))) float f32x2;

#define T_TOK 2048
#define HD    2048
#define NH    32
#define NKV   16
#define DKh   128
#define DVh   128

// ---------- helpers ----------
__device__ __forceinline__ void bf2f(uint32_t u, float& a, float& b) {
    union { uint32_t i; float f; } x;
    x.i = u << 16;          a = x.f;
    x.i = u & 0xffff0000u;  b = x.f;
}

__device__ __forceinline__ void gload16(const void* g, void* l) {
    __builtin_amdgcn_global_load_lds(
        (const __attribute__((address_space(1))) void*)g,
        (__attribute__((address_space(3))) void*)l, 16, 0, 0);
}

__device__ __forceinline__ void store_c(bf16* C, size_t off, float v) { C[off] = __float2bfloat16(v); }
__device__ __forceinline__ void store_c(float* C, size_t off, float v) { C[off] = v; }

// DPP butterfly add within rows of 16 lanes (VALU latency, no LDS)
template <int CTRL>
__device__ __forceinline__ float dppadd(float x) {
    int y = __builtin_amdgcn_update_dpp(0, __float_as_int(x), CTRL, 0xf, 0xf, true);
    return x + __int_as_float(y);
}
// quad interleaved 16-lane butterfly: four independent DPP chains pipeline,
// ~1 chain of latency for 4 reductions.
__device__ __forceinline__ void red16x4(float& a, float& b, float& c, float& d) {
    a = dppadd<0xB1>(a);  b = dppadd<0xB1>(b);  c = dppadd<0xB1>(c);  d = dppadd<0xB1>(d);
    a = dppadd<0x4E>(a);  b = dppadd<0x4E>(b);  c = dppadd<0x4E>(c);  d = dppadd<0x4E>(d);
    a = dppadd<0x141>(a); b = dppadd<0x141>(b); c = dppadd<0x141>(c); d = dppadd<0x141>(d);
    a = dppadd<0x140>(a); b = dppadd<0x140>(b); c = dppadd<0x140>(c); d = dppadd<0x140>(d);
}

__device__ __forceinline__ f32x2 pkfma(f32x2 a, f32x2 b, f32x2 c) {
    return __builtin_elementwise_fma(a, b, c);
}
__device__ __forceinline__ f32x2 sp2(float x) { return f32x2{x, x}; }

// ---------- convert fp32 -> bf16 elementwise ----------
__global__ __launch_bounds__(256) void f2b_kernel(
    const float* __restrict__ in, bf16* __restrict__ out, int n)
{
    int i = blockIdx.x * 256 + threadIdx.x;
    if (i < n) out[i] = __float2bfloat16(in[i]);
}

// ---------- transpose+convert: in fp32 [R][C] -> out bf16 [C][R] ----------
__global__ __launch_bounds__(256) void transpose_kernel(
    const float* __restrict__ in, bf16* __restrict__ out, int R, int C)
{
    __shared__ bf16 tile[32][33];
    int c0 = blockIdx.x * 32, r0 = blockIdx.y * 32;
    int x = threadIdx.x;
    int y = threadIdx.y;
    #pragma unroll
    for (int i = y; i < 32; i += 8)
        tile[i][x] = __float2bfloat16(in[(size_t)(r0 + i) * C + c0 + x]);
    __syncthreads();
    #pragma unroll
    for (int i = y; i < 32; i += 8)
        out[(size_t)(c0 + i) * R + r0 + x] = tile[x][i];
}

// ---------- build [Wa|Wb|0] transposed: out bf16 [128][2048] ----------
__global__ __launch_bounds__(256) void build_wab_kernel(
    const float* __restrict__ Wa, const float* __restrict__ Wb, bf16* __restrict__ out)
{
    int k = blockIdx.x * 256 + threadIdx.x;
    int n = blockIdx.y;
    float v = 0.f;
    if (n < 32)      v = Wa[(size_t)k * 32 + n];
    else if (n < 64) v = Wb[(size_t)k * 32 + (n - 32)];
    out[(size_t)n * 2048 + k] = __float2bfloat16(v);
}

// ---------- MFMA GEMM: C[M,N] = A[M,K] * B^T (B given as [N,K]), bf16 in ----------
template <typename OutT>
__global__ __launch_bounds__(256) void gemm_bt_kernel(
    const bf16* __restrict__ A, const bf16* __restrict__ B, OutT* __restrict__ C,
    int M, int N, int K)
{
    __shared__ short sA[128 * 64];
    __shared__ short sB[128 * 64];
    const int tid  = threadIdx.x;
    const int w    = tid >> 6;
    const int lane = tid & 63;
    const int quad = lane >> 4;
    const int r    = lane & 15;
    const int wm   = w >> 1, wn = w & 1;
    const int bm   = blockIdx.x, bn = blockIdx.y;
    const int lrow = lane >> 3;
    const int lp   = lane & 7;
    const int lc   = lp ^ lrow;

    f32x4 acc[4][4] = {};

    const int nkb = K >> 6;
    for (int kb = 0; kb < nkb; ++kb) {
        __syncthreads();
        #pragma unroll
        for (int it = 0; it < 4; ++it) {
            int grp = w * 4 + it;
            int rr  = grp * 8 + lrow;
            const bf16* ga = A + (size_t)(bm * 128 + rr) * K + kb * 64 + lc * 8;
            gload16(ga, (void*)(sA + grp * 512));
            const bf16* gb = B + (size_t)(bn * 128 + rr) * K + kb * 64 + lc * 8;
            gload16(gb, (void*)(sB + grp * 512));
        }
        __syncthreads();

        #pragma unroll
        for (int kk = 0; kk < 2; ++kk) {
            short8 av[4], bv[4];
            #pragma unroll
            for (int i = 0; i < 4; ++i) {
                int p   = (kk * 4 + quad) ^ (r & 7);
                int row = wm * 64 + i * 16 + r;
                av[i] = *(const short8*)(sA + row * 64 + p * 8);
                int rowb = wn * 64 + i * 16 + r;
                bv[i] = *(const short8*)(sB + rowb * 64 + p * 8);
            }
            #pragma unroll
            for (int i = 0; i < 4; ++i)
                #pragma unroll
                for (int j = 0; j < 4; ++j)
                    acc[i][j] = __builtin_amdgcn_mfma_f32_16x16x32_bf16(
                        av[i], bv[j], acc[i][j], 0, 0, 0);
        }
    }

    #pragma unroll
    for (int i = 0; i < 4; ++i) {
        int row0 = bm * 128 + wm * 64 + i * 16 + quad * 4;
        #pragma unroll
        for (int j = 0; j < 4; ++j) {
            int col = bn * 128 + wn * 64 + j * 16 + r;
            #pragma unroll
            for (int e = 0; e < 4; ++e)
                store_c(C, (size_t)(row0 + e) * N + col, acc[i][j][e]);
        }
    }
}

// ---------- conv+silu+l2norm for q AND k (one block per (t,hkv)) ------------
// Also computes qk[t][hkv] = qn . kn (post-norm, incl. DK^-0.5) and writes it
// into word 3 of the packed gate buffer pk4[h][t][4] for both GQA heads.
__global__ __launch_bounds__(128) void conv_qk_kernel(
    const bf16* __restrict__ mixed, const float* __restrict__ cq,
    const float* __restrict__ ck, float* __restrict__ qn, float* __restrict__ kn,
    float* __restrict__ pk4)
{
    int t   = blockIdx.x;
    int hkv = blockIdx.y;
    int d   = threadIdx.x;
    int cl  = hkv * DKh + d;
    float aq = 0.f, ak = 0.f;
    #pragma unroll
    for (int j = 0; j < 4; ++j) {
        int ts = t - 3 + j;
        if (ts >= 0) {
            aq += __bfloat162float(mixed[(size_t)ts * 8192 + cl])        * cq[cl * 4 + j];
            ak += __bfloat162float(mixed[(size_t)ts * 8192 + 2048 + cl]) * ck[cl * 4 + j];
        }
    }
    float sq = aq / (1.f + __expf(-aq));   // silu
    float sk = ak / (1.f + __expf(-ak));
    float s0 = sq * sq, s1 = sk * sk, s2 = sq * sk;
    #pragma unroll
    for (int m = 1; m < 64; m <<= 1) {
        s0 += __shfl_xor(s0, m, 64);
        s1 += __shfl_xor(s1, m, 64);
        s2 += __shfl_xor(s2, m, 64);
    }
    __shared__ float part[6];
    if ((threadIdx.x & 63) == 0) {
        int w = threadIdx.x >> 6;
        part[w * 3 + 0] = s0; part[w * 3 + 1] = s1; part[w * 3 + 2] = s2;
    }
    __syncthreads();
    float sumq = part[0] + part[3];
    float sumk = part[1] + part[4];
    float sqk  = part[2] + part[5];
    float rnq = rsqrtf(sumq + 1e-6f);
    float rnk = rsqrtf(sumk + 1e-6f);
    const float scale = 0.08838834764831845f;           // DK^-0.5 folded into q
    qn[(size_t)t * 2048 + cl] = sq * rnq * scale;
    kn[(size_t)t * 2048 + cl] = sk * rnk;
    if (d == 0) {
        float qk = sqk * rnq * rnk * scale;             // qn . kn
        pk4[((size_t)(2 * hkv)     * T_TOK + t) * 4 + 3] = qk;
        pk4[((size_t)(2 * hkv + 1) * T_TOK + t) * 4 + 3] = qk;
    }
}

// ---------- conv+silu for v ----------
__global__ __launch_bounds__(256) void conv_v_kernel(
    const bf16* __restrict__ mixed, const float* __restrict__ cv, bf16* __restrict__ vv)
{
    int idx = blockIdx.x * 256 + threadIdx.x;
    int t = idx >> 12, c = idx & 4095;
    float acc = 0.f;
    #pragma unroll
    for (int j = 0; j < 4; ++j) {
        int ts = t - 3 + j;
        if (ts >= 0)
            acc += __bfloat162float(mixed[(size_t)ts * 8192 + 4096 + c]) * cv[c * 4 + j];
    }
    vv[idx] = __float2bfloat16(acc / (1.f + __expf(-acc)));
}

// ---------- gating: pack pk4[h][t][{e^g, -beta*e^g, beta, (qk)}] -------------
// word 3 (qk) is written by conv_qk_kernel — do NOT touch it here.
__global__ __launch_bounds__(256) void gating_kernel(
    const float* __restrict__ ab, const float* __restrict__ dt_bias,
    const float* __restrict__ A_log, float* __restrict__ pk4)
{
    int i = blockIdx.x * 256 + threadIdx.x;
    int h = i >> 11, t = i & 2047;
    float a  = ab[(size_t)t * 128 + h] + dt_bias[h];
    float sp = (a <= 20.f) ? log1pf(__expf(a)) : a;
    float gg = -__expf(A_log[h]) * sp;
    float b  = ab[(size_t)t * 128 + 32 + h];
    float eg = __expf(gg);
    float be = 1.f / (1.f + __expf(-b));
    size_t base = ((size_t)h * T_TOK + t) * 4;
    pk4[base + 0] = eg;
    pk4[base + 1] = -be * eg;
    pk4[base + 2] = be;
}

// ---------- gated delta-rule recurrence (v6) --------------------------------
// Round-5 PMC forensics: step = 504cy, VALU busy 222cy, per-CU register-load
// traffic 21KB/step (~330cy at 64B/cy L1 return) -> L1-RETURN-BW BOUND on
// redundant loads (16 dvl lanes reload identical k/q; g4 loaded per-thread
// though block-uniform). v6: dv_pt=2 — thread owns 8dk x 2dv (S = 8 f32x2
// packed along dv), block 128 = 16dkg x 8dvl (16 dv), grid (32,8) = 1
// block/CU (2 waves on 2 SIMDs). Halves per-CU kq traffic; gates staged
// once into LDS ([h][t][4] layout, 32KB, broadcast ds_read per step); v/o as
// u32 bf16-pairs. Dot chains produce both dv columns per pkfma; one
// interleaved 4-way DPP butterfly reduces d1/d2 for both columns.
__device__ __forceinline__ void gdn_step(
    f32x2 S[8], const float kf[8], const float qf[8],
    float es, float ns, float qk, float bv0, float bv1,
    uint32_t* optr, bool writer)
{
    // dots off S_old: f32x2 accumulators carry {dv0, dv1} simultaneously
    f32x2 pa = S[0] * sp2(kf[0]);
    f32x2 pb = S[1] * sp2(kf[1]);
    f32x2 qa_ = S[0] * sp2(qf[0]);
    f32x2 qb_ = S[1] * sp2(qf[1]);
    pa = pkfma(S[2], sp2(kf[2]), pa);  pb = pkfma(S[3], sp2(kf[3]), pb);
    qa_ = pkfma(S[2], sp2(qf[2]), qa_); qb_ = pkfma(S[3], sp2(qf[3]), qb_);
    pa = pkfma(S[4], sp2(kf[4]), pa);  pb = pkfma(S[5], sp2(kf[5]), pb);
    qa_ = pkfma(S[4], sp2(qf[4]), qa_); qb_ = pkfma(S[5], sp2(qf[5]), qb_);
    pa = pkfma(S[6], sp2(kf[6]), pa);  pb = pkfma(S[7], sp2(kf[7]), pb);
    qa_ = pkfma(S[6], sp2(qf[6]), qa_); qb_ = pkfma(S[7], sp2(qf[7]), qb_);
    f32x2 d1 = pa + pb;
    f32x2 d2 = qa_ + qb_;
    float d1a = d1.x, d1b = d1.y, d2a = d2.x, d2b = d2.y;
    // decay-scale of S overlaps the reductions (independent)
    f32x2 e2 = sp2(es);
    f32x2 Se[8];
    #pragma unroll
    for (int j = 0; j < 8; ++j) Se[j] = S[j] * e2;
    red16x4(d1a, d1b, d2a, d2b);
    float dvv0 = fmaf(ns, d1a, bv0);        // beta*(v0 - e^g*d1a)
    float dvv1 = fmaf(ns, d1b, bv1);
    f32x2 dv2 = {dvv0, dvv1};
    #pragma unroll
    for (int j = 0; j < 8; ++j) S[j] = pkfma(sp2(kf[j]), dv2, Se[j]);
    if (writer) {
        float o0 = fmaf(qk, dvv0, es * d2a);
        float o1 = fmaf(qk, dvv1, es * d2b);
        union { bf16 h2[2]; uint32_t u; } p;
        p.h2[0] = __float2bfloat16(o0);
        p.h2[1] = __float2bfloat16(o1);
        *optr = p.u;
    }
}

#define PF_DEPTH 4

__global__ __launch_bounds__(128, 1) void recur_kernel(
    const float* __restrict__ qn, const float* __restrict__ kn, const bf16* __restrict__ vv,
    const float* __restrict__ pk4, bf16* __restrict__ o)
{
    __shared__ float sgate[(T_TOK + PF_DEPTH) * 4];   // ~32.1 KB
    int h   = blockIdx.x;          // 0..31
    int sp  = blockIdx.y;          // 0..7
    int tid = threadIdx.x;
    int dvl = tid >> 4;            // 0..7
    int dkg = tid & 15;            // 0..15 : dk = dkg*8 .. +8
    int dv0 = sp * 16 + dvl * 2;   // thread owns dv0, dv0+1
    int hkv = h >> 1;              // GQA repeat-interleave
    bool writer = (dkg == 0);

    // stage this head's gates into LDS (coalesced 16B/thread)
    {
        const float* gp = pk4 + (size_t)h * T_TOK * 4;
        for (int i = tid; i < T_TOK; i += 128)
            *(float4*)(sgate + (size_t)i * 4) = *(const float4*)(gp + (size_t)i * 4);
        if (tid < PF_DEPTH * 4) sgate[T_TOK * 4 + tid] = 0.f;   // pad rows
    }
    __syncthreads();

    const float*    kp   = kn + hkv * DKh + dkg * 8;
    const float*    qp   = qn + hkv * DKh + dkg * 8;
    const uint32_t* vp   = (const uint32_t*)(vv + h * DVh + dv0);   // 2 bf16/row
    uint32_t*       ob32 = (uint32_t*)(o + h * DVh + dv0);

    f32x2 S[8] = {};

    // prefetch slots (rows t .. t+3). OOB global reads (up to 4 rows past each
    // array end) land in the adjacent workspace allocation / pad; unused.
    float4 ka[PF_DEPTH], kb[PF_DEPTH], qa[PF_DEPTH], qb[PF_DEPTH];
    float  es_[PF_DEPTH], ns_[PF_DEPTH], qs_[PF_DEPTH], b0_[PF_DEPTH], b1_[PF_DEPTH];
    #pragma unroll
    for (int s = 0; s < PF_DEPTH; ++s) {
        ka[s] = *(const float4*)(kp + (size_t)s * 2048);
        kb[s] = *(const float4*)(kp + (size_t)s * 2048 + 4);
        qa[s] = *(const float4*)(qp + (size_t)s * 2048);
        qb[s] = *(const float4*)(qp + (size_t)s * 2048 + 4);
        float4 g4 = *(const float4*)(sgate + (size_t)s * 4);
        uint32_t vu = vp[(size_t)s * 2048];
        float v0f, v1f; bf2f(vu, v0f, v1f);
        es_[s] = g4.x; ns_[s] = g4.y; qs_[s] = g4.w;
        b0_[s] = g4.z * v0f; b1_[s] = g4.z * v1f;
    }
    const float*    kl = kp + (size_t)PF_DEPTH * 2048;
    const float*    ql = qp + (size_t)PF_DEPTH * 2048;
    const uint32_t* vl = vp + (size_t)PF_DEPTH * 2048;

    #pragma unroll 1
    for (int t = 0; t < T_TOK; t += PF_DEPTH) {
        #pragma unroll
        for (int s = 0; s < PF_DEPTH; ++s) {
            float kf[8] = {ka[s].x, ka[s].y, ka[s].z, ka[s].w,
                           kb[s].x, kb[s].y, kb[s].z, kb[s].w};
            float qf[8] = {qa[s].x, qa[s].y, qa[s].z, qa[s].w,
                           qb[s].x, qb[s].y, qb[s].z, qb[s].w};
            float egt = es_[s], nbt = ns_[s], qkt = qs_[s];
            float bv0 = b0_[s], bv1 = b1_[s];
            // refill slot s with row t+s+PF_DEPTH (pad-covered when OOB)
            ka[s] = *(const float4*)(kl + (size_t)s * 2048);
            kb[s] = *(const float4*)(kl + (size_t)s * 2048 + 4);
            qa[s] = *(const float4*)(ql + (size_t)s * 2048);
            qb[s] = *(const float4*)(ql + (size_t)s * 2048 + 4);
            float4 g4 = *(const float4*)(sgate + (size_t)(t + s + PF_DEPTH) * 4);
            uint32_t vu = vl[(size_t)s * 2048];
            float v0f, v1f; bf2f(vu, v0f, v1f);
            es_[s] = g4.x; ns_[s] = g4.y; qs_[s] = g4.w;
            b0_[s] = g4.z * v0f; b1_[s] = g4.z * v1f;
            gdn_step(S, kf, qf, egt, nbt, qkt, bv0, bv1,
                     ob32 + (size_t)(t + s) * 2048, writer);
        }
        kl += (size_t)PF_DEPTH * 2048;
        ql += (size_t)PF_DEPTH * 2048;
        vl += (size_t)PF_DEPTH * 2048;
    }
}

// ---------- gated RMSNorm ----------
__global__ __launch_bounds__(256) void normgate_kernel(
    const bf16* __restrict__ o, const bf16* __restrict__ gate,
    const float* __restrict__ w, bf16* __restrict__ og)
{
    int grp  = blockIdx.x * 4 + (threadIdx.x >> 6);
    int lane = threadIdx.x & 63;
    int t = grp >> 5, h = grp & 31;
    size_t base = (size_t)t * 4096 + h * DVh;
    uint32_t uo = *(const uint32_t*)(o + base + lane * 2);
    float a, b; bf2f(uo, a, b);
    float ss = a * a + b * b;
    #pragma unroll
    for (int m = 1; m < 64; m <<= 1) ss += __shfl_xor(ss, m, 64);
    float rn = rsqrtf(ss * (1.f / 128.f) + 1e-5f);
    uint32_t ug = *(const uint32_t*)(gate + base + lane * 2);
    float ga, gb; bf2f(ug, ga, gb);
    float wa = w[lane * 2], wb = w[lane * 2 + 1];
    float oa = a * rn * wa * (ga / (1.f + __expf(-ga)));
    float ob = b * rn * wb * (gb / (1.f + __expf(-gb)));
    og[base + lane * 2]     = __float2bfloat16(oa);
    og[base + lane * 2 + 1] = __float2bfloat16(ob);
}

// ---------- launch ----------
extern "C" void kernel_launch(void* const* d_in, const int* in_sizes, int n_in,
                              void* d_out, int out_size, void* d_ws, size_t ws_size,
                              hipStream_t stream)
{
    const float* h       = (const float*)d_in[0];
    const float* Wq      = (const float*)d_in[1];
    const float* Wk      = (const float*)d_in[2];
    const float* Wv      = (const float*)d_in[3];
    const float* Wa      = (const float*)d_in[4];
    const float* Wb      = (const float*)d_in[5];
    const float* Wg      = (const float*)d_in[6];
    const float* conv_q  = (const float*)d_in[7];
    const float* conv_k  = (const float*)d_in[8];
    const float* conv_v  = (const float*)d_in[9];
    const float* dt_bias = (const float*)d_in[10];
    const float* A_log   = (const float*)d_in[11];
    const float* onw     = (const float*)d_in[12];
    const float* Wo      = (const float*)d_in[13];
    float* out = (float*)d_out;

    char* ws = (char*)d_ws;
    bf16*  WqkvT = (bf16*)ws;   ws += (size_t)8192 * 2048 * 2;   // 33.5 MB
    bf16*  WgT   = (bf16*)ws;   ws += (size_t)4096 * 2048 * 2;   // 16.8 MB (reused as qnb)
    bf16*  WoT   = (bf16*)ws;   ws += (size_t)2048 * 4096 * 2;   // 16.8 MB
    bf16*  WabT  = (bf16*)ws;   ws += (size_t)128 * 2048 * 2;
    bf16*  hb    = (bf16*)ws;   ws += (size_t)2048 * 2048 * 2;
    bf16*  mixed = (bf16*)ws;   ws += (size_t)2048 * 8192 * 2;   // 33.5 MB
    float* ab    = (float*)ws;  ws += (size_t)2048 * 128 * 4;
    float* knb   = (float*)ws;  ws += (size_t)2048 * 2048 * 4;   // 16.8 MB fp32
    bf16*  vvb   = (bf16*)ws;   ws += (size_t)2048 * 4096 * 2;   // 16.8 MB
    float* pk4   = (float*)ws;  ws += (size_t)NH * T_TOK * 4 * 4; // [h][t][{eg,-b*eg,b,qk}]
    ws += 32768;                                                 // OOB-prefetch pad
    // aliases over dead regions (stream-ordered lifetimes):
    float* qnb = (float*)WgT;                      // WgT dead after gate GEMM
    bf16*  ob   = WqkvT;                           // WqkvT dead after qkv GEMM
    bf16*  gate = WqkvT + (size_t)2048 * 4096;     // second half of WqkvT region
    bf16*  og   = mixed;                           // mixed dead after conv kernels

    dim3 tb(32, 8);
    transpose_kernel<<<dim3(64, 64),  tb, 0, stream>>>(Wq, WqkvT,                       2048, 2048);
    transpose_kernel<<<dim3(64, 64),  tb, 0, stream>>>(Wk, WqkvT + (size_t)2048 * 2048, 2048, 2048);
    transpose_kernel<<<dim3(128, 64), tb, 0, stream>>>(Wv, WqkvT + (size_t)4096 * 2048, 2048, 4096);
    transpose_kernel<<<dim3(128, 64), tb, 0, stream>>>(Wg, WgT,                         2048, 4096);
    transpose_kernel<<<dim3(64, 128), tb, 0, stream>>>(Wo, WoT,                         4096, 2048);
    build_wab_kernel<<<dim3(8, 128), 256, 0, stream>>>(Wa, Wb, WabT);
    f2b_kernel<<<16384, 256, 0, stream>>>(h, hb, 2048 * 2048);

    gemm_bt_kernel<bf16> <<<dim3(16, 64), 256, 0, stream>>>(hb, WqkvT, mixed, 2048, 8192, 2048);
    gemm_bt_kernel<float><<<dim3(16, 1),  256, 0, stream>>>(hb, WabT,  ab,    2048, 128,  2048);
    gemm_bt_kernel<bf16> <<<dim3(16, 32), 256, 0, stream>>>(hb, WgT,   gate,  2048, 4096, 2048);

    conv_qk_kernel<<<dim3(2048, 16), 128, 0, stream>>>(mixed, conv_q, conv_k, qnb, knb, pk4);
    conv_v_kernel<<<32768, 256, 0, stream>>>(mixed, conv_v, vvb);
    gating_kernel<<<256, 256, 0, stream>>>(ab, dt_bias, A_log, pk4);

    recur_kernel<<<dim3(32, 8), 128, 0, stream>>>(qnb, knb, vvb, pk4, ob);
    normgate_kernel<<<16384, 256, 0, stream>>>(ob, gate, onw, og);

    gemm_bt_kernel<float><<<dim3(16, 16), 256, 0, stream>>>(og, WoT, out, 2048, 2048, 4096);
}

// Round 8
// 951.578 us; speedup vs baseline: 1.1794x; 1.1794x over previous
//
#include <hip/hip_runtime.h>
#include <hip/hip_bf16.h>
#include <stdint.h>
#include <stddef.h>

using bf16 = __hip_bfloat16;
typedef __attribute__((ext_vector_type(8))) short short8;   // 8 bf16 (4 VGPRs)
typedef __attribute__((ext_vector_type(4))) float f32x4;
typedef __attribute__((ext_vector_type(2))) float f32x2;

#define T_TOK 2048
#define HD    2048
#define NH    32
#define NKV   16
#define DKh   128
#define DVh   128

// ---------- helpers ----------
__device__ __forceinline__ void bf2f(uint32_t u, float& a, float& b) {
    union { uint32_t i; float f; } x;
    x.i = u << 16;          a = x.f;
    x.i = u & 0xffff0000u;  b = x.f;
}

__device__ __forceinline__ void gload16(const void* g, void* l) {
    __builtin_amdgcn_global_load_lds(
        (const __attribute__((address_space(1))) void*)g,
        (__attribute__((address_space(3))) void*)l, 16, 0, 0);
}

__device__ __forceinline__ void store_c(bf16* C, size_t off, float v) { C[off] = __float2bfloat16(v); }
__device__ __forceinline__ void store_c(float* C, size_t off, float v) { C[off] = v; }

// DPP butterfly add within rows of 16 lanes (VALU latency, no LDS)
template <int CTRL>
__device__ __forceinline__ float dppadd(float x) {
    int y = __builtin_amdgcn_update_dpp(0, __float_as_int(x), CTRL, 0xf, 0xf, true);
    return x + __int_as_float(y);
}
// dual interleaved 16-lane butterfly: two independent DPP chains pipeline,
// ~1 chain of latency for 2 reductions.
__device__ __forceinline__ void red16x2(float& x, float& y) {
    x = dppadd<0xB1>(x);  y = dppadd<0xB1>(y);    // xor 1
    x = dppadd<0x4E>(x);  y = dppadd<0x4E>(y);    // xor 2
    x = dppadd<0x141>(x); y = dppadd<0x141>(y);   // xor 4
    x = dppadd<0x140>(x); y = dppadd<0x140>(y);   // xor 8
}

__device__ __forceinline__ f32x2 pkfma(f32x2 a, f32x2 b, f32x2 c) {
    return __builtin_elementwise_fma(a, b, c);
}

// ---------- convert fp32 -> bf16 elementwise ----------
__global__ __launch_bounds__(256) void f2b_kernel(
    const float* __restrict__ in, bf16* __restrict__ out, int n)
{
    int i = blockIdx.x * 256 + threadIdx.x;
    if (i < n) out[i] = __float2bfloat16(in[i]);
}

// ---------- transpose+convert: in fp32 [R][C] -> out bf16 [C][R] ----------
__global__ __launch_bounds__(256) void transpose_kernel(
    const float* __restrict__ in, bf16* __restrict__ out, int R, int C)
{
    __shared__ bf16 tile[32][33];
    int c0 = blockIdx.x * 32, r0 = blockIdx.y * 32;
    int x = threadIdx.x;
    int y = threadIdx.y;
    #pragma unroll
    for (int i = y; i < 32; i += 8)
        tile[i][x] = __float2bfloat16(in[(size_t)(r0 + i) * C + c0 + x]);
    __syncthreads();
    #pragma unroll
    for (int i = y; i < 32; i += 8)
        out[(size_t)(c0 + i) * R + r0 + x] = tile[x][i];
}

// ---------- build [Wa|Wb|0] transposed: out bf16 [128][2048] ----------
__global__ __launch_bounds__(256) void build_wab_kernel(
    const float* __restrict__ Wa, const float* __restrict__ Wb, bf16* __restrict__ out)
{
    int k = blockIdx.x * 256 + threadIdx.x;
    int n = blockIdx.y;
    float v = 0.f;
    if (n < 32)      v = Wa[(size_t)k * 32 + n];
    else if (n < 64) v = Wb[(size_t)k * 32 + (n - 32)];
    out[(size_t)n * 2048 + k] = __float2bfloat16(v);
}

// ---------- MFMA GEMM: C[M,N] = A[M,K] * B^T (B given as [N,K]), bf16 in ----------
template <typename OutT>
__global__ __launch_bounds__(256) void gemm_bt_kernel(
    const bf16* __restrict__ A, const bf16* __restrict__ B, OutT* __restrict__ C,
    int M, int N, int K)
{
    __shared__ short sA[128 * 64];
    __shared__ short sB[128 * 64];
    const int tid  = threadIdx.x;
    const int w    = tid >> 6;
    const int lane = tid & 63;
    const int quad = lane >> 4;
    const int r    = lane & 15;
    const int wm   = w >> 1, wn = w & 1;
    const int bm   = blockIdx.x, bn = blockIdx.y;
    const int lrow = lane >> 3;
    const int lp   = lane & 7;
    const int lc   = lp ^ lrow;

    f32x4 acc[4][4] = {};

    const int nkb = K >> 6;
    for (int kb = 0; kb < nkb; ++kb) {
        __syncthreads();
        #pragma unroll
        for (int it = 0; it < 4; ++it) {
            int grp = w * 4 + it;
            int rr  = grp * 8 + lrow;
            const bf16* ga = A + (size_t)(bm * 128 + rr) * K + kb * 64 + lc * 8;
            gload16(ga, (void*)(sA + grp * 512));
            const bf16* gb = B + (size_t)(bn * 128 + rr) * K + kb * 64 + lc * 8;
            gload16(gb, (void*)(sB + grp * 512));
        }
        __syncthreads();

        #pragma unroll
        for (int kk = 0; kk < 2; ++kk) {
            short8 av[4], bv[4];
            #pragma unroll
            for (int i = 0; i < 4; ++i) {
                int p   = (kk * 4 + quad) ^ (r & 7);
                int row = wm * 64 + i * 16 + r;
                av[i] = *(const short8*)(sA + row * 64 + p * 8);
                int rowb = wn * 64 + i * 16 + r;
                bv[i] = *(const short8*)(sB + rowb * 64 + p * 8);
            }
            #pragma unroll
            for (int i = 0; i < 4; ++i)
                #pragma unroll
                for (int j = 0; j < 4; ++j)
                    acc[i][j] = __builtin_amdgcn_mfma_f32_16x16x32_bf16(
                        av[i], bv[j], acc[i][j], 0, 0, 0);
        }
    }

    #pragma unroll
    for (int i = 0; i < 4; ++i) {
        int row0 = bm * 128 + wm * 64 + i * 16 + quad * 4;
        #pragma unroll
        for (int j = 0; j < 4; ++j) {
            int col = bn * 128 + wn * 64 + j * 16 + r;
            #pragma unroll
            for (int e = 0; e < 4; ++e)
                store_c(C, (size_t)(row0 + e) * N + col, acc[i][j][e]);
        }
    }
}

// ---------- conv+silu+l2norm for q AND k (one block per (t,hkv)) ------------
// Also computes qk[t][hkv] = qn . kn (post-norm, incl. DK^-0.5) and writes it
// into word 3 of the packed gate buffer pk4[h][t][4] for both GQA heads.
__global__ __launch_bounds__(128) void conv_qk_kernel(
    const bf16* __restrict__ mixed, const float* __restrict__ cq,
    const float* __restrict__ ck, float* __restrict__ qn, float* __restrict__ kn,
    float* __restrict__ pk4)
{
    int t   = blockIdx.x;
    int hkv = blockIdx.y;
    int d   = threadIdx.x;
    int cl  = hkv * DKh + d;
    float aq = 0.f, ak = 0.f;
    #pragma unroll
    for (int j = 0; j < 4; ++j) {
        int ts = t - 3 + j;
        if (ts >= 0) {
            aq += __bfloat162float(mixed[(size_t)ts * 8192 + cl])        * cq[cl * 4 + j];
            ak += __bfloat162float(mixed[(size_t)ts * 8192 + 2048 + cl]) * ck[cl * 4 + j];
        }
    }
    float sq = aq / (1.f + __expf(-aq));   // silu
    float sk = ak / (1.f + __expf(-ak));
    float s0 = sq * sq, s1 = sk * sk, s2 = sq * sk;
    #pragma unroll
    for (int m = 1; m < 64; m <<= 1) {
        s0 += __shfl_xor(s0, m, 64);
        s1 += __shfl_xor(s1, m, 64);
        s2 += __shfl_xor(s2, m, 64);
    }
    __shared__ float part[6];
    if ((threadIdx.x & 63) == 0) {
        int w = threadIdx.x >> 6;
        part[w * 3 + 0] = s0; part[w * 3 + 1] = s1; part[w * 3 + 2] = s2;
    }
    __syncthreads();
    float sumq = part[0] + part[3];
    float sumk = part[1] + part[4];
    float sqk  = part[2] + part[5];
    float rnq = rsqrtf(sumq + 1e-6f);
    float rnk = rsqrtf(sumk + 1e-6f);
    const float scale = 0.08838834764831845f;           // DK^-0.5 folded into q
    qn[(size_t)t * 2048 + cl] = sq * rnq * scale;
    kn[(size_t)t * 2048 + cl] = sk * rnk;
    if (d == 0) {
        float qk = sqk * rnq * rnk * scale;             // qn . kn
        pk4[((size_t)(2 * hkv)     * T_TOK + t) * 4 + 3] = qk;
        pk4[((size_t)(2 * hkv + 1) * T_TOK + t) * 4 + 3] = qk;
    }
}

// ---------- conv+silu for v ----------
__global__ __launch_bounds__(256) void conv_v_kernel(
    const bf16* __restrict__ mixed, const float* __restrict__ cv, bf16* __restrict__ vv)
{
    int idx = blockIdx.x * 256 + threadIdx.x;
    int t = idx >> 12, c = idx & 4095;
    float acc = 0.f;
    #pragma unroll
    for (int j = 0; j < 4; ++j) {
        int ts = t - 3 + j;
        if (ts >= 0)
            acc += __bfloat162float(mixed[(size_t)ts * 8192 + 4096 + c]) * cv[c * 4 + j];
    }
    vv[idx] = __float2bfloat16(acc / (1.f + __expf(-acc)));
}

// ---------- gating: pack pk4[h][t][{e^g, -beta*e^g, beta, (qk)}] -------------
// word 3 (qk) is written by conv_qk_kernel — do NOT touch it here.
__global__ __launch_bounds__(256) void gating_kernel(
    const float* __restrict__ ab, const float* __restrict__ dt_bias,
    const float* __restrict__ A_log, float* __restrict__ pk4)
{
    int i = blockIdx.x * 256 + threadIdx.x;
    int h = i >> 11, t = i & 2047;
    float a  = ab[(size_t)t * 128 + h] + dt_bias[h];
    float sp = (a <= 20.f) ? log1pf(__expf(a)) : a;
    float gg = -__expf(A_log[h]) * sp;
    float b  = ab[(size_t)t * 128 + 32 + h];
    float eg = __expf(gg);
    float be = 1.f / (1.f + __expf(-b));
    size_t base = ((size_t)h * T_TOK + t) * 4;
    pk4[base + 0] = eg;
    pk4[base + 1] = -be * eg;
    pk4[base + 2] = be;
}

// ---------- gated delta-rule recurrence (v7) --------------------------------
// Forensics r5-r7: a fixed ~280cy/step gap survives chain-halving (v5),
// traffic-halving (v6), and launch_bounds (r3) => the register prefetch
// pipeline never materializes — the allocator (108-112 VGPR vs >=128 needed)
// sinks refill loads to their uses, exposing an L2 round trip every step.
// v7: the prefetch lives in LDS via global_load_lds (async DMA, zero VGPR —
// cannot be sunk). Double-buffered TILE=16-token tiles: per tile each wave
// issues 4 staging instrs (per-lane global addrs mix kn/qn; wave0 stages v,
// wave1 gates), then 16 steps read LDS; one __syncthreads per tile (drains
// vmcnt). Thread dkg owns dk {dkg*4..+4} u {64+dkg*4..+4} — an equivalent
// dk partition making the 4 ds_read_b128/step 2-way-aliased only (free).
// Compute structure = v5 (dual dot off S_old, red16x2, o off-chain).
__device__ __forceinline__ void gdn_step(
    f32x2 S[4], float4 kfa, float4 kfb, float4 qfa, float4 qfb,
    float egt, float nbt, float bvt, float qkt, bf16* optr, bool writer)
{
    f32x2 k2[4] = {{kfa.x, kfa.y}, {kfa.z, kfa.w}, {kfb.x, kfb.y}, {kfb.z, kfb.w}};
    f32x2 q2[4] = {{qfa.x, qfa.y}, {qfa.z, qfa.w}, {qfb.x, qfb.y}, {qfb.z, qfb.w}};
    // two independent dots off S_old
    f32x2 pd = pkfma(S[1], k2[1], S[0] * k2[0]);
    f32x2 pe = pkfma(S[3], k2[3], S[2] * k2[2]);
    f32x2 qd = pkfma(S[1], q2[1], S[0] * q2[0]);
    f32x2 qe = pkfma(S[3], q2[3], S[2] * q2[2]);
    // decay-scale of S: independent of the reductions, overlaps them
    f32x2 e2 = {egt, egt};
    f32x2 Se0 = S[0] * e2, Se1 = S[1] * e2, Se2 = S[2] * e2, Se3 = S[3] * e2;
    f32x2 ps = pd + pe;
    f32x2 qs = qd + qe;
    float d1 = ps.x + ps.y;
    float d2 = qs.x + qs.y;
    red16x2(d1, d2);
    float dvv = fmaf(nbt, d1, bvt);          // beta*(v - e^g*d1)
    f32x2 dv2 = {dvv, dvv};
    S[0] = pkfma(k2[0], dv2, Se0);
    S[1] = pkfma(k2[1], dv2, Se1);
    S[2] = pkfma(k2[2], dv2, Se2);
    S[3] = pkfma(k2[3], dv2, Se3);
    if (writer) *optr = __float2bfloat16(fmaf(qkt, dvv, egt * d2));
}

#define TILE 16

__global__ __launch_bounds__(256, 1) void recur_kernel(
    const float* __restrict__ qn, const float* __restrict__ kn, const bf16* __restrict__ vv,
    const float* __restrict__ pk4, bf16* __restrict__ o)
{
    __shared__ float    skq[2][TILE][256];   // [buf][tok][k0..127|q0..127] = 32 KB
    __shared__ float    sgt[2][TILE][4];     // [buf][tok][eg,-b*eg,b,qk]   = 512 B
    __shared__ uint16_t sv2[2][TILE][16];    // [buf][tok][16 dv bf16]      = 1 KB

    int h    = blockIdx.x;          // 0..31
    int sp   = blockIdx.y;          // 0..7
    int tid  = threadIdx.x;
    int dvl  = tid >> 4;            // 0..15
    int dkg  = tid & 15;            // 0..15
    int dv   = sp * 16 + dvl;
    int hkv  = h >> 1;              // GQA repeat-interleave
    int wave = tid >> 6;            // 0..3
    int lane = tid & 63;
    bool writer = (dkg == 0);

    bf16* optr = o + (size_t)h * DVh + dv;

    // per-lane global source for k/q staging (lane<32 -> k, lane>=32 -> q)
    const float* kqsrc = (lane < 32)
        ? (kn + (size_t)hkv * DKh + (size_t)lane * 4)
        : (qn + (size_t)hkv * DKh + (size_t)(lane - 32) * 4);
    const bf16*  vsrc  = vv + (size_t)h * DVh + sp * 16 + (size_t)(lane & 1) * 8;
    const float* gsrc  = pk4 + ((size_t)h * T_TOK) * 4;

    f32x2 S[4] = {};

    // stage tile [t0, t0+TILE) into buffer b. OOB reads on the final prefetch
    // (rows 2048..2063) land in adjacent live workspace allocations; unused.
    auto stage = [&](int b, int t0) {
        #pragma unroll
        for (int i = 0; i < 4; ++i) {
            int tok = wave * 4 + i;
            gload16(kqsrc + (size_t)(t0 + tok) * 2048, (void*)&skq[b][tok][0]);
        }
        if (wave == 0) {
            if (lane < 32)
                gload16(vsrc + (size_t)(t0 + (lane >> 1)) * 4096, (void*)&sv2[b][0][0]);
        } else if (wave == 1) {
            if (lane < 16)
                gload16(gsrc + (size_t)(t0 + lane) * 4, (void*)&sgt[b][0][0]);
        }
    };

    stage(0, 0);
    __syncthreads();                 // drains vmcnt -> tile 0 visible

    int buf = 0;
    #pragma unroll 1
    for (int t0 = 0; t0 < T_TOK; t0 += TILE) {
        stage(buf ^ 1, t0 + TILE);   // async prefetch next tile (no VGPR cost)
        #pragma unroll
        for (int s = 0; s < TILE; ++s) {
            const float* tokp = &skq[buf][s][0];
            float4 kA = *(const float4*)(tokp + dkg * 4);          // dk dkg*4..+4
            float4 kB = *(const float4*)(tokp + 64 + dkg * 4);     // dk 64+dkg*4..+4
            float4 qA = *(const float4*)(tokp + 128 + dkg * 4);
            float4 qB = *(const float4*)(tokp + 192 + dkg * 4);
            float4 g4 = *(const float4*)(&sgt[buf][s][0]);         // broadcast
            uint32_t vu = sv2[buf][s][dvl];
            float vf = __uint_as_float(vu << 16);                  // bf16 -> f32
            float bvt = g4.z * vf;
            gdn_step(S, kA, kB, qA, qB, g4.x, g4.y, bvt, g4.w,
                     optr + (size_t)(t0 + s) * 4096, writer);
        }
        __syncthreads();             // all waves done reading + next tile landed
        buf ^= 1;
    }
}

// ---------- gated RMSNorm ----------
__global__ __launch_bounds__(256) void normgate_kernel(
    const bf16* __restrict__ o, const bf16* __restrict__ gate,
    const float* __restrict__ w, bf16* __restrict__ og)
{
    int grp  = blockIdx.x * 4 + (threadIdx.x >> 6);
    int lane = threadIdx.x & 63;
    int t = grp >> 5, h = grp & 31;
    size_t base = (size_t)t * 4096 + h * DVh;
    uint32_t uo = *(const uint32_t*)(o + base + lane * 2);
    float a, b; bf2f(uo, a, b);
    float ss = a * a + b * b;
    #pragma unroll
    for (int m = 1; m < 64; m <<= 1) ss += __shfl_xor(ss, m, 64);
    float rn = rsqrtf(ss * (1.f / 128.f) + 1e-5f);
    uint32_t ug = *(const uint32_t*)(gate + base + lane * 2);
    float ga, gb; bf2f(ug, ga, gb);
    float wa = w[lane * 2], wb = w[lane * 2 + 1];
    float oa = a * rn * wa * (ga / (1.f + __expf(-ga)));
    float ob = b * rn * wb * (gb / (1.f + __expf(-gb)));
    og[base + lane * 2]     = __float2bfloat16(oa);
    og[base + lane * 2 + 1] = __float2bfloat16(ob);
}

// ---------- launch ----------
extern "C" void kernel_launch(void* const* d_in, const int* in_sizes, int n_in,
                              void* d_out, int out_size, void* d_ws, size_t ws_size,
                              hipStream_t stream)
{
    const float* h       = (const float*)d_in[0];
    const float* Wq      = (const float*)d_in[1];
    const float* Wk      = (const float*)d_in[2];
    const float* Wv      = (const float*)d_in[3];
    const float* Wa      = (const float*)d_in[4];
    const float* Wb      = (const float*)d_in[5];
    const float* Wg      = (const float*)d_in[6];
    const float* conv_q  = (const float*)d_in[7];
    const float* conv_k  = (const float*)d_in[8];
    const float* conv_v  = (const float*)d_in[9];
    const float* dt_bias = (const float*)d_in[10];
    const float* A_log   = (const float*)d_in[11];
    const float* onw     = (const float*)d_in[12];
    const float* Wo      = (const float*)d_in[13];
    float* out = (float*)d_out;

    char* ws = (char*)d_ws;
    bf16*  WqkvT = (bf16*)ws;   ws += (size_t)8192 * 2048 * 2;   // 33.5 MB
    bf16*  WgT   = (bf16*)ws;   ws += (size_t)4096 * 2048 * 2;   // 16.8 MB (reused as qnb)
    bf16*  WoT   = (bf16*)ws;   ws += (size_t)2048 * 4096 * 2;   // 16.8 MB
    bf16*  WabT  = (bf16*)ws;   ws += (size_t)128 * 2048 * 2;
    bf16*  hb    = (bf16*)ws;   ws += (size_t)2048 * 2048 * 2;
    bf16*  mixed = (bf16*)ws;   ws += (size_t)2048 * 8192 * 2;   // 33.5 MB
    float* ab    = (float*)ws;  ws += (size_t)2048 * 128 * 4;
    float* knb   = (float*)ws;  ws += (size_t)2048 * 2048 * 4;   // 16.8 MB fp32
    bf16*  vvb   = (bf16*)ws;   ws += (size_t)2048 * 4096 * 2;   // 16.8 MB
    float* pk4   = (float*)ws;  ws += (size_t)NH * T_TOK * 4 * 4; // [h][t][{eg,-b*eg,b,qk}]
    ws += 32768;                                                 // OOB-prefetch pad
    // aliases over dead regions (stream-ordered lifetimes):
    float* qnb = (float*)WgT;                      // WgT dead after gate GEMM
    bf16*  ob   = WqkvT;                           // WqkvT dead after qkv GEMM
    bf16*  gate = WqkvT + (size_t)2048 * 4096;     // second half of WqkvT region
    bf16*  og   = mixed;                           // mixed dead after conv kernels

    dim3 tb(32, 8);
    transpose_kernel<<<dim3(64, 64),  tb, 0, stream>>>(Wq, WqkvT,                       2048, 2048);
    transpose_kernel<<<dim3(64, 64),  tb, 0, stream>>>(Wk, WqkvT + (size_t)2048 * 2048, 2048, 2048);
    transpose_kernel<<<dim3(128, 64), tb, 0, stream>>>(Wv, WqkvT + (size_t)4096 * 2048, 2048, 4096);
    transpose_kernel<<<dim3(128, 64), tb, 0, stream>>>(Wg, WgT,                         2048, 4096);
    transpose_kernel<<<dim3(64, 128), tb, 0, stream>>>(Wo, WoT,                         4096, 2048);
    build_wab_kernel<<<dim3(8, 128), 256, 0, stream>>>(Wa, Wb, WabT);
    f2b_kernel<<<16384, 256, 0, stream>>>(h, hb, 2048 * 2048);

    gemm_bt_kernel<bf16> <<<dim3(16, 64), 256, 0, stream>>>(hb, WqkvT, mixed, 2048, 8192, 2048);
    gemm_bt_kernel<float><<<dim3(16, 1),  256, 0, stream>>>(hb, WabT,  ab,    2048, 128,  2048);
    gemm_bt_kernel<bf16> <<<dim3(16, 32), 256, 0, stream>>>(hb, WgT,   gate,  2048, 4096, 2048);

    conv_qk_kernel<<<dim3(2048, 16), 128, 0, stream>>>(mixed, conv_q, conv_k, qnb, knb, pk4);
    conv_v_kernel<<<32768, 256, 0, stream>>>(mixed, conv_v, vvb);
    gating_kernel<<<256, 256, 0, stream>>>(ab, dt_bias, A_log, pk4);

    recur_kernel<<<dim3(32, 8), 256, 0, stream>>>(qnb, knb, vvb, pk4, ob);
    normgate_kernel<<<16384, 256, 0, stream>>>(ob, gate, onw, og);

    gemm_bt_kernel<float><<<dim3(16, 16), 256, 0, stream>>>(og, WoT, out, 2048, 2048, 4096);
}

// Round 9
// 910.218 us; speedup vs baseline: 1.2330x; 1.0454x over previous
//
#include <hip/hip_runtime.h>
#include <hip/hip_bf16.h>
#include <stdint.h>
#include <stddef.h>

using bf16 = __hip_bfloat16;
typedef __attribute__((ext_vector_type(8))) short short8;   // 8 bf16 (4 VGPRs)
typedef __attribute__((ext_vector_type(4))) float f32x4;
typedef __attribute__((ext_vector_type(2))) float f32x2;

#define T_TOK 2048
#define HD    2048
#define NH    32
#define NKV   16
#define DKh   128
#define DVh   128

// ---------- helpers ----------
__device__ __forceinline__ void bf2f(uint32_t u, float& a, float& b) {
    union { uint32_t i; float f; } x;
    x.i = u << 16;          a = x.f;
    x.i = u & 0xffff0000u;  b = x.f;
}

__device__ __forceinline__ void gload16(const void* g, void* l) {
    __builtin_amdgcn_global_load_lds(
        (const __attribute__((address_space(1))) void*)g,
        (__attribute__((address_space(3))) void*)l, 16, 0, 0);
}

__device__ __forceinline__ void store_c(bf16* C, size_t off, float v) { C[off] = __float2bfloat16(v); }
__device__ __forceinline__ void store_c(float* C, size_t off, float v) { C[off] = v; }

// DPP butterfly add within rows of 16 lanes (VALU latency, no LDS)
template <int CTRL>
__device__ __forceinline__ float dppadd(float x) {
    int y = __builtin_amdgcn_update_dpp(0, __float_as_int(x), CTRL, 0xf, 0xf, true);
    return x + __int_as_float(y);
}
// quad interleaved 16-lane butterfly: four independent DPP chains pipeline,
// ~1 chain of latency for 4 reductions.
__device__ __forceinline__ void red16x4(float& a, float& b, float& c, float& d) {
    a = dppadd<0xB1>(a);  b = dppadd<0xB1>(b);  c = dppadd<0xB1>(c);  d = dppadd<0xB1>(d);
    a = dppadd<0x4E>(a);  b = dppadd<0x4E>(b);  c = dppadd<0x4E>(c);  d = dppadd<0x4E>(d);
    a = dppadd<0x141>(a); b = dppadd<0x141>(b); c = dppadd<0x141>(c); d = dppadd<0x141>(d);
    a = dppadd<0x140>(a); b = dppadd<0x140>(b); c = dppadd<0x140>(c); d = dppadd<0x140>(d);
}

__device__ __forceinline__ f32x2 pkfma(f32x2 a, f32x2 b, f32x2 c) {
    return __builtin_elementwise_fma(a, b, c);
}
__device__ __forceinline__ f32x2 sp2(float x) { return f32x2{x, x}; }

// ---------- convert fp32 -> bf16 elementwise ----------
__global__ __launch_bounds__(256) void f2b_kernel(
    const float* __restrict__ in, bf16* __restrict__ out, int n)
{
    int i = blockIdx.x * 256 + threadIdx.x;
    if (i < n) out[i] = __float2bfloat16(in[i]);
}

// ---------- transpose+convert: in fp32 [R][C] -> out bf16 [C][R] ----------
__global__ __launch_bounds__(256) void transpose_kernel(
    const float* __restrict__ in, bf16* __restrict__ out, int R, int C)
{
    __shared__ bf16 tile[32][33];
    int c0 = blockIdx.x * 32, r0 = blockIdx.y * 32;
    int x = threadIdx.x;
    int y = threadIdx.y;
    #pragma unroll
    for (int i = y; i < 32; i += 8)
        tile[i][x] = __float2bfloat16(in[(size_t)(r0 + i) * C + c0 + x]);
    __syncthreads();
    #pragma unroll
    for (int i = y; i < 32; i += 8)
        out[(size_t)(c0 + i) * R + r0 + x] = tile[x][i];
}

// ---------- build [Wa|Wb|0] transposed: out bf16 [128][2048] ----------
__global__ __launch_bounds__(256) void build_wab_kernel(
    const float* __restrict__ Wa, const float* __restrict__ Wb, bf16* __restrict__ out)
{
    int k = blockIdx.x * 256 + threadIdx.x;
    int n = blockIdx.y;
    float v = 0.f;
    if (n < 32)      v = Wa[(size_t)k * 32 + n];
    else if (n < 64) v = Wb[(size_t)k * 32 + (n - 32)];
    out[(size_t)n * 2048 + k] = __float2bfloat16(v);
}

// ---------- MFMA GEMM: C[M,N] = A[M,K] * B^T (B given as [N,K]), bf16 in ----------
template <typename OutT>
__global__ __launch_bounds__(256) void gemm_bt_kernel(
    const bf16* __restrict__ A, const bf16* __restrict__ B, OutT* __restrict__ C,
    int M, int N, int K)
{
    __shared__ short sA[128 * 64];
    __shared__ short sB[128 * 64];
    const int tid  = threadIdx.x;
    const int w    = tid >> 6;
    const int lane = tid & 63;
    const int quad = lane >> 4;
    const int r    = lane & 15;
    const int wm   = w >> 1, wn = w & 1;
    const int bm   = blockIdx.x, bn = blockIdx.y;
    const int lrow = lane >> 3;
    const int lp   = lane & 7;
    const int lc   = lp ^ lrow;

    f32x4 acc[4][4] = {};

    const int nkb = K >> 6;
    for (int kb = 0; kb < nkb; ++kb) {
        __syncthreads();
        #pragma unroll
        for (int it = 0; it < 4; ++it) {
            int grp = w * 4 + it;
            int rr  = grp * 8 + lrow;
            const bf16* ga = A + (size_t)(bm * 128 + rr) * K + kb * 64 + lc * 8;
            gload16(ga, (void*)(sA + grp * 512));
            const bf16* gb = B + (size_t)(bn * 128 + rr) * K + kb * 64 + lc * 8;
            gload16(gb, (void*)(sB + grp * 512));
        }
        __syncthreads();

        #pragma unroll
        for (int kk = 0; kk < 2; ++kk) {
            short8 av[4], bv[4];
            #pragma unroll
            for (int i = 0; i < 4; ++i) {
                int p   = (kk * 4 + quad) ^ (r & 7);
                int row = wm * 64 + i * 16 + r;
                av[i] = *(const short8*)(sA + row * 64 + p * 8);
                int rowb = wn * 64 + i * 16 + r;
                bv[i] = *(const short8*)(sB + rowb * 64 + p * 8);
            }
            #pragma unroll
            for (int i = 0; i < 4; ++i)
                #pragma unroll
                for (int j = 0; j < 4; ++j)
                    acc[i][j] = __builtin_amdgcn_mfma_f32_16x16x32_bf16(
                        av[i], bv[j], acc[i][j], 0, 0, 0);
        }
    }

    #pragma unroll
    for (int i = 0; i < 4; ++i) {
        int row0 = bm * 128 + wm * 64 + i * 16 + quad * 4;
        #pragma unroll
        for (int j = 0; j < 4; ++j) {
            int col = bn * 128 + wn * 64 + j * 16 + r;
            #pragma unroll
            for (int e = 0; e < 4; ++e)
                store_c(C, (size_t)(row0 + e) * N + col, acc[i][j][e]);
        }
    }
}

// ---------- conv+silu+l2norm for q AND k (one block per (t,hkv)) ------------
// Also computes qk[t][hkv] = qn . kn (post-norm, incl. DK^-0.5) and writes it
// into word 3 of the packed gate buffer pk4[h][t][4] for both GQA heads.
__global__ __launch_bounds__(128) void conv_qk_kernel(
    const bf16* __restrict__ mixed, const float* __restrict__ cq,
    const float* __restrict__ ck, float* __restrict__ qn, float* __restrict__ kn,
    float* __restrict__ pk4)
{
    int t   = blockIdx.x;
    int hkv = blockIdx.y;
    int d   = threadIdx.x;
    int cl  = hkv * DKh + d;
    float aq = 0.f, ak = 0.f;
    #pragma unroll
    for (int j = 0; j < 4; ++j) {
        int ts = t - 3 + j;
        if (ts >= 0) {
            aq += __bfloat162float(mixed[(size_t)ts * 8192 + cl])        * cq[cl * 4 + j];
            ak += __bfloat162float(mixed[(size_t)ts * 8192 + 2048 + cl]) * ck[cl * 4 + j];
        }
    }
    float sq = aq / (1.f + __expf(-aq));   // silu
    float sk = ak / (1.f + __expf(-ak));
    float s0 = sq * sq, s1 = sk * sk, s2 = sq * sk;
    #pragma unroll
    for (int m = 1; m < 64; m <<= 1) {
        s0 += __shfl_xor(s0, m, 64);
        s1 += __shfl_xor(s1, m, 64);
        s2 += __shfl_xor(s2, m, 64);
    }
    __shared__ float part[6];
    if ((threadIdx.x & 63) == 0) {
        int w = threadIdx.x >> 6;
        part[w * 3 + 0] = s0; part[w * 3 + 1] = s1; part[w * 3 + 2] = s2;
    }
    __syncthreads();
    float sumq = part[0] + part[3];
    float sumk = part[1] + part[4];
    float sqk  = part[2] + part[5];
    float rnq = rsqrtf(sumq + 1e-6f);
    float rnk = rsqrtf(sumk + 1e-6f);
    const float scale = 0.08838834764831845f;           // DK^-0.5 folded into q
    qn[(size_t)t * 2048 + cl] = sq * rnq * scale;
    kn[(size_t)t * 2048 + cl] = sk * rnk;
    if (d == 0) {
        float qk = sqk * rnq * rnk * scale;             // qn . kn
        pk4[((size_t)(2 * hkv)     * T_TOK + t) * 4 + 3] = qk;
        pk4[((size_t)(2 * hkv + 1) * T_TOK + t) * 4 + 3] = qk;
    }
}

// ---------- cross terms for pair-lookahead: pcx[h][t][{k_t.k_{t-1}, q_t.k_{t-1}}]
// Only odd t is consumed by recur (pair trailer); grid covers odd t only.
__global__ __launch_bounds__(128) void xterm_kernel(
    const float* __restrict__ qn, const float* __restrict__ kn, float* __restrict__ pcx)
{
    int t   = blockIdx.x * 2 + 1;          // odd tokens
    int hkv = blockIdx.y;
    int cl  = hkv * DKh + threadIdx.x;
    float kc = kn[(size_t)t * 2048 + cl];
    float kp = kn[(size_t)(t - 1) * 2048 + cl];
    float qc = qn[(size_t)t * 2048 + cl];
    float s1 = kc * kp, s2 = qc * kp;
    #pragma unroll
    for (int m = 1; m < 64; m <<= 1) {
        s1 += __shfl_xor(s1, m, 64);
        s2 += __shfl_xor(s2, m, 64);
    }
    __shared__ float part[4];
    if ((threadIdx.x & 63) == 0) {
        int w = threadIdx.x >> 6;
        part[w * 2 + 0] = s1; part[w * 2 + 1] = s2;
    }
    __syncthreads();
    if (threadIdx.x == 0) {
        float kk = part[0] + part[2];
        float qp = part[1] + part[3];
        size_t b0 = ((size_t)(2 * hkv)     * T_TOK + t) * 2;
        size_t b1 = ((size_t)(2 * hkv + 1) * T_TOK + t) * 2;
        pcx[b0] = kk; pcx[b0 + 1] = qp;
        pcx[b1] = kk; pcx[b1 + 1] = qp;
    }
}

// ---------- conv+silu for v ----------
__global__ __launch_bounds__(256) void conv_v_kernel(
    const bf16* __restrict__ mixed, const float* __restrict__ cv, bf16* __restrict__ vv)
{
    int idx = blockIdx.x * 256 + threadIdx.x;
    int t = idx >> 12, c = idx & 4095;
    float acc = 0.f;
    #pragma unroll
    for (int j = 0; j < 4; ++j) {
        int ts = t - 3 + j;
        if (ts >= 0)
            acc += __bfloat162float(mixed[(size_t)ts * 8192 + 4096 + c]) * cv[c * 4 + j];
    }
    vv[idx] = __float2bfloat16(acc / (1.f + __expf(-acc)));
}

// ---------- gating: pack pk4[h][t][{e^g, -beta*e^g, beta, (qk)}] -------------
// word 3 (qk) is written by conv_qk_kernel — do NOT touch it here.
__global__ __launch_bounds__(256) void gating_kernel(
    const float* __restrict__ ab, const float* __restrict__ dt_bias,
    const float* __restrict__ A_log, float* __restrict__ pk4)
{
    int i = blockIdx.x * 256 + threadIdx.x;
    int h = i >> 11, t = i & 2047;
    float a  = ab[(size_t)t * 128 + h] + dt_bias[h];
    float sp = (a <= 20.f) ? log1pf(__expf(a)) : a;
    float gg = -__expf(A_log[h]) * sp;
    float b  = ab[(size_t)t * 128 + 32 + h];
    float eg = __expf(gg);
    float be = 1.f / (1.f + __expf(-b));
    size_t base = ((size_t)h * T_TOK + t) * 4;
    pk4[base + 0] = eg;
    pk4[base + 1] = -be * eg;
    pk4[base + 2] = be;
}

// ---------- gated delta-rule recurrence (v9: token-pair lookahead) ----------
// v7 forensics: step = 490cy, VALU 166cy, stall ~324cy at 1 wave/SIMD
// (structural cap) — per-step lgkmcnt wait on LDS reads (~120), dependent
// DPP-hazard chain (~80-100), misc dep stalls. All are PER CHAIN TRAVERSAL.
// v9 processes TWO tokens per traversal via the delta-rule expansion:
//   dvv0 = fma(-b0*e0, k0.S0, b0*v0)
//   k1.S1 = e0*(k1.S0) + (k1.k0)*dvv0 ;  q1.S1 = e0*(q1.S0) + (q1.k0)*dvv0
//   S2 = (e0*e1)*S0 + (e1*dvv0)*k0 + dvv1*k1
// All four dots run off S0 concurrently -> ONE red16x4 traversal per pair;
// serial part is ~4 scalar FMAs. Cross terms (k1.k0, q1.k0) are
// S-independent, precomputed by xterm_kernel. LDS staging = v7 (proven).
#define TILE 16

__global__ __launch_bounds__(256, 1) void recur_kernel(
    const float* __restrict__ qn, const float* __restrict__ kn, const bf16* __restrict__ vv,
    const float* __restrict__ pk4, const float* __restrict__ pcx, bf16* __restrict__ o)
{
    __shared__ float    skq[2][TILE][256];   // [buf][tok][k0..127|q0..127] = 32 KB
    __shared__ float    sgt[2][TILE][4];     // [buf][tok][eg,-b*eg,b,qk]   = 512 B
    __shared__ float    sgx[2][TILE][2];     // [buf][tok][kk,qkp] (odd t)  = 256 B
    __shared__ uint16_t sv2[2][TILE][16];    // [buf][tok][16 dv bf16]      = 1 KB

    int h    = blockIdx.x;          // 0..31
    int sp   = blockIdx.y;          // 0..7
    int tid  = threadIdx.x;
    int dvl  = tid >> 4;            // 0..15
    int dkg  = tid & 15;            // 0..15
    int dv   = sp * 16 + dvl;
    int hkv  = h >> 1;              // GQA repeat-interleave
    int wave = tid >> 6;            // 0..3
    int lane = tid & 63;
    bool writer = (dkg == 0);

    bf16* optr = o + (size_t)h * DVh + dv;

    // per-lane global source for k/q staging (lane<32 -> k, lane>=32 -> q)
    const float* kqsrc = (lane < 32)
        ? (kn + (size_t)hkv * DKh + (size_t)lane * 4)
        : (qn + (size_t)hkv * DKh + (size_t)(lane - 32) * 4);
    const bf16*  vsrc  = vv + (size_t)h * DVh + sp * 16 + (size_t)(lane & 1) * 8;
    const float* gsrc  = pk4 + ((size_t)h * T_TOK) * 4;
    const float* xsrc  = pcx + ((size_t)h * T_TOK) * 2;

    f32x2 S[4] = {};

    // stage tile [t0, t0+TILE) into buffer b. OOB reads on the final prefetch
    // (rows 2048..2063) land in adjacent live workspace allocations; unused.
    auto stage = [&](int b, int t0) {
        #pragma unroll
        for (int i = 0; i < 4; ++i) {
            int tok = wave * 4 + i;
            gload16(kqsrc + (size_t)(t0 + tok) * 2048, (void*)&skq[b][tok][0]);
        }
        if (wave == 0) {
            if (lane < 32)
                gload16(vsrc + (size_t)(t0 + (lane >> 1)) * 4096, (void*)&sv2[b][0][0]);
        } else if (wave == 1) {
            if (lane < 16)
                gload16(gsrc + (size_t)(t0 + lane) * 4, (void*)&sgt[b][0][0]);
        } else if (wave == 2) {
            if (lane < 8)
                gload16(xsrc + (size_t)(t0 + lane * 2) * 2, (void*)&sgx[b][0][0]);
        }
    };

    stage(0, 0);
    __syncthreads();                 // drains vmcnt -> tile 0 visible

    int buf = 0;
    #pragma unroll 1
    for (int t0 = 0; t0 < T_TOK; t0 += TILE) {
        stage(buf ^ 1, t0 + TILE);   // async prefetch next tile (no VGPR cost)
        #pragma unroll
        for (int p = 0; p < TILE / 2; ++p) {
            int s0 = 2 * p, s1 = s0 + 1;
            const float* tp0 = &skq[buf][s0][0];
            const float* tp1 = &skq[buf][s1][0];
            f32x2 k0[4], q0[4], k1[4], q1[4];
            {
                float4 a = *(const float4*)(tp0 + dkg * 4);
                float4 b = *(const float4*)(tp0 + 64 + dkg * 4);
                float4 c = *(const float4*)(tp0 + 128 + dkg * 4);
                float4 d = *(const float4*)(tp0 + 192 + dkg * 4);
                k0[0] = {a.x, a.y}; k0[1] = {a.z, a.w}; k0[2] = {b.x, b.y}; k0[3] = {b.z, b.w};
                q0[0] = {c.x, c.y}; q0[1] = {c.z, c.w}; q0[2] = {d.x, d.y}; q0[3] = {d.z, d.w};
            }
            {
                float4 a = *(const float4*)(tp1 + dkg * 4);
                float4 b = *(const float4*)(tp1 + 64 + dkg * 4);
                float4 c = *(const float4*)(tp1 + 128 + dkg * 4);
                float4 d = *(const float4*)(tp1 + 192 + dkg * 4);
                k1[0] = {a.x, a.y}; k1[1] = {a.z, a.w}; k1[2] = {b.x, b.y}; k1[3] = {b.z, b.w};
                q1[0] = {c.x, c.y}; q1[1] = {c.z, c.w}; q1[2] = {d.x, d.y}; q1[3] = {d.z, d.w};
            }
            float4 g0 = *(const float4*)(&sgt[buf][s0][0]);
            float4 g1 = *(const float4*)(&sgt[buf][s1][0]);
            float2 cx = *(const float2*)(&sgx[buf][s1][0]);   // {k1.k0, q1.k0}
            float v0 = __uint_as_float((uint32_t)sv2[buf][s0][dvl] << 16);
            float v1 = __uint_as_float((uint32_t)sv2[buf][s1][dvl] << 16);

            // four dots off S0 (full ILP)
            f32x2 pa = pkfma(S[1], k0[1], S[0] * k0[0]);
            f32x2 pb = pkfma(S[3], k0[3], S[2] * k0[2]);
            f32x2 qa = pkfma(S[1], q0[1], S[0] * q0[0]);
            f32x2 qb = pkfma(S[3], q0[3], S[2] * q0[2]);
            f32x2 ra = pkfma(S[1], k1[1], S[0] * k1[0]);
            f32x2 rb = pkfma(S[3], k1[3], S[2] * k1[2]);
            f32x2 sa = pkfma(S[1], q1[1], S[0] * q1[0]);
            f32x2 sb = pkfma(S[3], q1[3], S[2] * q1[2]);
            f32x2 ps = pa + pb, qs = qa + qb, rs = ra + rb, ss = sa + sb;
            float D1a = ps.x + ps.y;      // k0.S0 (partial -> reduced)
            float D2a = qs.x + qs.y;      // q0.S0
            float D1b = rs.x + rs.y;      // k1.S0
            float D2b = ss.x + ss.y;      // q1.S0
            red16x4(D1a, D2a, D1b, D2b);

            // serial scalar part (short chain)
            float bv0  = g0.z * v0;
            float bv1  = g1.z * v1;
            float dvv0 = fmaf(g0.y, D1a, bv0);            // b0*(v0 - e0*D1a)
            float d1b  = fmaf(cx.x, dvv0, g0.x * D1b);    // k1.S1
            float dvv1 = fmaf(g1.y, d1b, bv1);            // b1*(v1 - e1*(k1.S1))

            // S update: S2 = (e0*e1)S0 + (e1*dvv0)k0 + dvv1*k1
            f32x2 eev = sp2(g0.x * g1.x);
            f32x2 d0v = sp2(dvv0 * g1.x);
            f32x2 d1v = sp2(dvv1);
            S[0] = pkfma(k1[0], d1v, pkfma(k0[0], d0v, S[0] * eev));
            S[1] = pkfma(k1[1], d1v, pkfma(k0[1], d0v, S[1] * eev));
            S[2] = pkfma(k1[2], d1v, pkfma(k0[2], d0v, S[2] * eev));
            S[3] = pkfma(k1[3], d1v, pkfma(k0[3], d0v, S[3] * eev));

            if (writer) {
                float o0  = fmaf(g0.w, dvv0, g0.x * D2a);
                float d2b = fmaf(cx.y, dvv0, g0.x * D2b);  // q1.S1
                float o1  = fmaf(g1.w, dvv1, g1.x * d2b);
                optr[(size_t)(t0 + s0) * 4096] = __float2bfloat16(o0);
                optr[(size_t)(t0 + s1) * 4096] = __float2bfloat16(o1);
            }
        }
        __syncthreads();             // all waves done reading + next tile landed
        buf ^= 1;
    }
}

// ---------- gated RMSNorm ----------
__global__ __launch_bounds__(256) void normgate_kernel(
    const bf16* __restrict__ o, const bf16* __restrict__ gate,
    const float* __restrict__ w, bf16* __restrict__ og)
{
    int grp  = blockIdx.x * 4 + (threadIdx.x >> 6);
    int lane = threadIdx.x & 63;
    int t = grp >> 5, h = grp & 31;
    size_t base = (size_t)t * 4096 + h * DVh;
    uint32_t uo = *(const uint32_t*)(o + base + lane * 2);
    float a, b; bf2f(uo, a, b);
    float ss = a * a + b * b;
    #pragma unroll
    for (int m = 1; m < 64; m <<= 1) ss += __shfl_xor(ss, m, 64);
    float rn = rsqrtf(ss * (1.f / 128.f) + 1e-5f);
    uint32_t ug = *(const uint32_t*)(gate + base + lane * 2);
    float ga, gb; bf2f(ug, ga, gb);
    float wa = w[lane * 2], wb = w[lane * 2 + 1];
    float oa = a * rn * wa * (ga / (1.f + __expf(-ga)));
    float ob = b * rn * wb * (gb / (1.f + __expf(-gb)));
    og[base + lane * 2]     = __float2bfloat16(oa);
    og[base + lane * 2 + 1] = __float2bfloat16(ob);
}

// ---------- launch ----------
extern "C" void kernel_launch(void* const* d_in, const int* in_sizes, int n_in,
                              void* d_out, int out_size, void* d_ws, size_t ws_size,
                              hipStream_t stream)
{
    const float* h       = (const float*)d_in[0];
    const float* Wq      = (const float*)d_in[1];
    const float* Wk      = (const float*)d_in[2];
    const float* Wv      = (const float*)d_in[3];
    const float* Wa      = (const float*)d_in[4];
    const float* Wb      = (const float*)d_in[5];
    const float* Wg      = (const float*)d_in[6];
    const float* conv_q  = (const float*)d_in[7];
    const float* conv_k  = (const float*)d_in[8];
    const float* conv_v  = (const float*)d_in[9];
    const float* dt_bias = (const float*)d_in[10];
    const float* A_log   = (const float*)d_in[11];
    const float* onw     = (const float*)d_in[12];
    const float* Wo      = (const float*)d_in[13];
    float* out = (float*)d_out;

    char* ws = (char*)d_ws;
    bf16*  WqkvT = (bf16*)ws;   ws += (size_t)8192 * 2048 * 2;   // 33.5 MB
    bf16*  WgT   = (bf16*)ws;   ws += (size_t)4096 * 2048 * 2;   // 16.8 MB (reused as qnb)
    bf16*  WoT   = (bf16*)ws;   ws += (size_t)2048 * 4096 * 2;   // 16.8 MB
    bf16*  WabT  = (bf16*)ws;   ws += (size_t)128 * 2048 * 2;
    bf16*  hb    = (bf16*)ws;   ws += (size_t)2048 * 2048 * 2;
    bf16*  mixed = (bf16*)ws;   ws += (size_t)2048 * 8192 * 2;   // 33.5 MB
    float* ab    = (float*)ws;  ws += (size_t)2048 * 128 * 4;
    float* knb   = (float*)ws;  ws += (size_t)2048 * 2048 * 4;   // 16.8 MB fp32
    bf16*  vvb   = (bf16*)ws;   ws += (size_t)2048 * 4096 * 2;   // 16.8 MB
    float* pk4   = (float*)ws;  ws += (size_t)NH * T_TOK * 4 * 4; // [h][t][{eg,-b*eg,b,qk}]
    float* pcx   = (float*)ws;  ws += (size_t)NH * T_TOK * 2 * 4; // [h][t][{kk,qkp}] (odd t)
    ws += 32768;                                                 // OOB-prefetch pad
    // aliases over dead regions (stream-ordered lifetimes):
    float* qnb = (float*)WgT;                      // WgT dead after gate GEMM
    bf16*  ob   = WqkvT;                           // WqkvT dead after qkv GEMM
    bf16*  gate = WqkvT + (size_t)2048 * 4096;     // second half of WqkvT region
    bf16*  og   = mixed;                           // mixed dead after conv kernels

    dim3 tb(32, 8);
    transpose_kernel<<<dim3(64, 64),  tb, 0, stream>>>(Wq, WqkvT,                       2048, 2048);
    transpose_kernel<<<dim3(64, 64),  tb, 0, stream>>>(Wk, WqkvT + (size_t)2048 * 2048, 2048, 2048);
    transpose_kernel<<<dim3(128, 64), tb, 0, stream>>>(Wv, WqkvT + (size_t)4096 * 2048, 2048, 4096);
    transpose_kernel<<<dim3(128, 64), tb, 0, stream>>>(Wg, WgT,                         2048, 4096);
    transpose_kernel<<<dim3(64, 128), tb, 0, stream>>>(Wo, WoT,                         4096, 2048);
    build_wab_kernel<<<dim3(8, 128), 256, 0, stream>>>(Wa, Wb, WabT);
    f2b_kernel<<<16384, 256, 0, stream>>>(h, hb, 2048 * 2048);

    gemm_bt_kernel<bf16> <<<dim3(16, 64), 256, 0, stream>>>(hb, WqkvT, mixed, 2048, 8192, 2048);
    gemm_bt_kernel<float><<<dim3(16, 1),  256, 0, stream>>>(hb, WabT,  ab,    2048, 128,  2048);
    gemm_bt_kernel<bf16> <<<dim3(16, 32), 256, 0, stream>>>(hb, WgT,   gate,  2048, 4096, 2048);

    conv_qk_kernel<<<dim3(2048, 16), 128, 0, stream>>>(mixed, conv_q, conv_k, qnb, knb, pk4);
    conv_v_kernel<<<32768, 256, 0, stream>>>(mixed, conv_v, vvb);
    gating_kernel<<<256, 256, 0, stream>>>(ab, dt_bias, A_log, pk4);
    xterm_kernel<<<dim3(1024, 16), 128, 0, stream>>>(qnb, knb, pcx);

    recur_kernel<<<dim3(32, 8), 256, 0, stream>>>(qnb, knb, vvb, pk4, pcx, ob);
    normgate_kernel<<<16384, 256, 0, stream>>>(ob, gate, onw, og);

    gemm_bt_kernel<float><<<dim3(16, 16), 256, 0, stream>>>(og, WoT, out, 2048, 2048, 4096);
}

// Round 10
// 895.230 us; speedup vs baseline: 1.2536x; 1.0167x over previous
//
#include <hip/hip_runtime.h>
#include <hip/hip_bf16.h>
#include <stdint.h>
#include <stddef.h>

using bf16 = __hip_bfloat16;
typedef __attribute__((ext_vector_type(8))) short short8;   // 8 bf16 (4 VGPRs)
typedef __attribute__((ext_vector_type(4))) float f32x4;
typedef __attribute__((ext_vector_type(2))) float f32x2;

#define T_TOK 2048
#define HD    2048
#define NH    32
#define NKV   16
#define DKh   128
#define DVh   128

// ---------- helpers ----------
__device__ __forceinline__ void bf2f(uint32_t u, float& a, float& b) {
    union { uint32_t i; float f; } x;
    x.i = u << 16;          a = x.f;
    x.i = u & 0xffff0000u;  b = x.f;
}

__device__ __forceinline__ void gload16(const void* g, void* l) {
    __builtin_amdgcn_global_load_lds(
        (const __attribute__((address_space(1))) void*)g,
        (__attribute__((address_space(3))) void*)l, 16, 0, 0);
}

__device__ __forceinline__ void store_c(bf16* C, size_t off, float v) { C[off] = __float2bfloat16(v); }
__device__ __forceinline__ void store_c(float* C, size_t off, float v) { C[off] = v; }

// DPP butterfly add within rows of 16 lanes (VALU latency, no LDS)
template <int CTRL>
__device__ __forceinline__ float dppadd(float x) {
    int y = __builtin_amdgcn_update_dpp(0, __float_as_int(x), CTRL, 0xf, 0xf, true);
    return x + __int_as_float(y);
}
// 8-way interleaved 16-lane butterfly: eight independent DPP chains pipeline;
// hazards fully hidden by chain interleave, ~issue-bound.
__device__ __forceinline__ void red16x8(float& a, float& b, float& c, float& d,
                                        float& e, float& f, float& g, float& h) {
    a = dppadd<0xB1>(a);  b = dppadd<0xB1>(b);  c = dppadd<0xB1>(c);  d = dppadd<0xB1>(d);
    e = dppadd<0xB1>(e);  f = dppadd<0xB1>(f);  g = dppadd<0xB1>(g);  h = dppadd<0xB1>(h);
    a = dppadd<0x4E>(a);  b = dppadd<0x4E>(b);  c = dppadd<0x4E>(c);  d = dppadd<0x4E>(d);
    e = dppadd<0x4E>(e);  f = dppadd<0x4E>(f);  g = dppadd<0x4E>(g);  h = dppadd<0x4E>(h);
    a = dppadd<0x141>(a); b = dppadd<0x141>(b); c = dppadd<0x141>(c); d = dppadd<0x141>(d);
    e = dppadd<0x141>(e); f = dppadd<0x141>(f); g = dppadd<0x141>(g); h = dppadd<0x141>(h);
    a = dppadd<0x140>(a); b = dppadd<0x140>(b); c = dppadd<0x140>(c); d = dppadd<0x140>(d);
    e = dppadd<0x140>(e); f = dppadd<0x140>(f); g = dppadd<0x140>(g); h = dppadd<0x140>(h);
}

__device__ __forceinline__ f32x2 pkfma(f32x2 a, f32x2 b, f32x2 c) {
    return __builtin_elementwise_fma(a, b, c);
}
__device__ __forceinline__ f32x2 sp2(float x) { return f32x2{x, x}; }

// ---------- convert fp32 -> bf16 elementwise ----------
__global__ __launch_bounds__(256) void f2b_kernel(
    const float* __restrict__ in, bf16* __restrict__ out, int n)
{
    int i = blockIdx.x * 256 + threadIdx.x;
    if (i < n) out[i] = __float2bfloat16(in[i]);
}

// ---------- transpose+convert: in fp32 [R][C] -> out bf16 [C][R] ----------
__global__ __launch_bounds__(256) void transpose_kernel(
    const float* __restrict__ in, bf16* __restrict__ out, int R, int C)
{
    __shared__ bf16 tile[32][33];
    int c0 = blockIdx.x * 32, r0 = blockIdx.y * 32;
    int x = threadIdx.x;
    int y = threadIdx.y;
    #pragma unroll
    for (int i = y; i < 32; i += 8)
        tile[i][x] = __float2bfloat16(in[(size_t)(r0 + i) * C + c0 + x]);
    __syncthreads();
    #pragma unroll
    for (int i = y; i < 32; i += 8)
        out[(size_t)(c0 + i) * R + r0 + x] = tile[x][i];
}

// ---------- build [Wa|Wb|0] transposed: out bf16 [128][2048] ----------
__global__ __launch_bounds__(256) void build_wab_kernel(
    const float* __restrict__ Wa, const float* __restrict__ Wb, bf16* __restrict__ out)
{
    int k = blockIdx.x * 256 + threadIdx.x;
    int n = blockIdx.y;
    float v = 0.f;
    if (n < 32)      v = Wa[(size_t)k * 32 + n];
    else if (n < 64) v = Wb[(size_t)k * 32 + (n - 32)];
    out[(size_t)n * 2048 + k] = __float2bfloat16(v);
}

// ---------- MFMA GEMM: C[M,N] = A[M,K] * B^T (B given as [N,K]), bf16 in ----------
template <typename OutT>
__global__ __launch_bounds__(256) void gemm_bt_kernel(
    const bf16* __restrict__ A, const bf16* __restrict__ B, OutT* __restrict__ C,
    int M, int N, int K)
{
    __shared__ short sA[128 * 64];
    __shared__ short sB[128 * 64];
    const int tid  = threadIdx.x;
    const int w    = tid >> 6;
    const int lane = tid & 63;
    const int quad = lane >> 4;
    const int r    = lane & 15;
    const int wm   = w >> 1, wn = w & 1;
    const int bm   = blockIdx.x, bn = blockIdx.y;
    const int lrow = lane >> 3;
    const int lp   = lane & 7;
    const int lc   = lp ^ lrow;

    f32x4 acc[4][4] = {};

    const int nkb = K >> 6;
    for (int kb = 0; kb < nkb; ++kb) {
        __syncthreads();
        #pragma unroll
        for (int it = 0; it < 4; ++it) {
            int grp = w * 4 + it;
            int rr  = grp * 8 + lrow;
            const bf16* ga = A + (size_t)(bm * 128 + rr) * K + kb * 64 + lc * 8;
            gload16(ga, (void*)(sA + grp * 512));
            const bf16* gb = B + (size_t)(bn * 128 + rr) * K + kb * 64 + lc * 8;
            gload16(gb, (void*)(sB + grp * 512));
        }
        __syncthreads();

        #pragma unroll
        for (int kk = 0; kk < 2; ++kk) {
            short8 av[4], bv[4];
            #pragma unroll
            for (int i = 0; i < 4; ++i) {
                int p   = (kk * 4 + quad) ^ (r & 7);
                int row = wm * 64 + i * 16 + r;
                av[i] = *(const short8*)(sA + row * 64 + p * 8);
                int rowb = wn * 64 + i * 16 + r;
                bv[i] = *(const short8*)(sB + rowb * 64 + p * 8);
            }
            #pragma unroll
            for (int i = 0; i < 4; ++i)
                #pragma unroll
                for (int j = 0; j < 4; ++j)
                    acc[i][j] = __builtin_amdgcn_mfma_f32_16x16x32_bf16(
                        av[i], bv[j], acc[i][j], 0, 0, 0);
        }
    }

    #pragma unroll
    for (int i = 0; i < 4; ++i) {
        int row0 = bm * 128 + wm * 64 + i * 16 + quad * 4;
        #pragma unroll
        for (int j = 0; j < 4; ++j) {
            int col = bn * 128 + wn * 64 + j * 16 + r;
            #pragma unroll
            for (int e = 0; e < 4; ++e)
                store_c(C, (size_t)(row0 + e) * N + col, acc[i][j][e]);
        }
    }
}

// ---------- conv+silu+l2norm for q AND k (one block per (t,hkv)) ------------
// Also computes qk[t][hkv] = qn . kn (post-norm, incl. DK^-0.5) and writes it
// into word 3 of the packed gate buffer pk4[h][t][4] for both GQA heads.
__global__ __launch_bounds__(128) void conv_qk_kernel(
    const bf16* __restrict__ mixed, const float* __restrict__ cq,
    const float* __restrict__ ck, float* __restrict__ qn, float* __restrict__ kn,
    float* __restrict__ pk4)
{
    int t   = blockIdx.x;
    int hkv = blockIdx.y;
    int d   = threadIdx.x;
    int cl  = hkv * DKh + d;
    float aq = 0.f, ak = 0.f;
    #pragma unroll
    for (int j = 0; j < 4; ++j) {
        int ts = t - 3 + j;
        if (ts >= 0) {
            aq += __bfloat162float(mixed[(size_t)ts * 8192 + cl])        * cq[cl * 4 + j];
            ak += __bfloat162float(mixed[(size_t)ts * 8192 + 2048 + cl]) * ck[cl * 4 + j];
        }
    }
    float sq = aq / (1.f + __expf(-aq));   // silu
    float sk = ak / (1.f + __expf(-ak));
    float s0 = sq * sq, s1 = sk * sk, s2 = sq * sk;
    #pragma unroll
    for (int m = 1; m < 64; m <<= 1) {
        s0 += __shfl_xor(s0, m, 64);
        s1 += __shfl_xor(s1, m, 64);
        s2 += __shfl_xor(s2, m, 64);
    }
    __shared__ float part[6];
    if ((threadIdx.x & 63) == 0) {
        int w = threadIdx.x >> 6;
        part[w * 3 + 0] = s0; part[w * 3 + 1] = s1; part[w * 3 + 2] = s2;
    }
    __syncthreads();
    float sumq = part[0] + part[3];
    float sumk = part[1] + part[4];
    float sqk  = part[2] + part[5];
    float rnq = rsqrtf(sumq + 1e-6f);
    float rnk = rsqrtf(sumk + 1e-6f);
    const float scale = 0.08838834764831845f;           // DK^-0.5 folded into q
    qn[(size_t)t * 2048 + cl] = sq * rnq * scale;
    kn[(size_t)t * 2048 + cl] = sk * rnk;
    if (d == 0) {
        float qk = sqk * rnq * rnk * scale;             // qn . kn
        pk4[((size_t)(2 * hkv)     * T_TOK + t) * 4 + 3] = qk;
        pk4[((size_t)(2 * hkv + 1) * T_TOK + t) * 4 + 3] = qk;
    }
}

// ---------- cross terms for 4-token lookahead -------------------------------
// For group g (tokens 4g..4g+3): pcx[h][g][12] =
// {kk10,kk20,kk21,kk30,kk31,kk32, qk10,qk20,qk21,qk30,qk31,qk32}
// where kkij = k_{4g+i}.k_{4g+j}, qkij = q_{4g+i}.k_{4g+j} (post-norm).
__global__ __launch_bounds__(128) void xterm_kernel(
    const float* __restrict__ qn, const float* __restrict__ kn, float* __restrict__ pcx)
{
    int g   = blockIdx.x;          // 0..511
    int hkv = blockIdx.y;
    int d   = threadIdx.x;
    int cl  = hkv * DKh + d;
    int t0  = g * 4;
    float k0 = kn[(size_t)(t0 + 0) * 2048 + cl];
    float k1 = kn[(size_t)(t0 + 1) * 2048 + cl];
    float k2 = kn[(size_t)(t0 + 2) * 2048 + cl];
    float k3 = kn[(size_t)(t0 + 3) * 2048 + cl];
    float q1 = qn[(size_t)(t0 + 1) * 2048 + cl];
    float q2 = qn[(size_t)(t0 + 2) * 2048 + cl];
    float q3 = qn[(size_t)(t0 + 3) * 2048 + cl];
    float s[12] = {k1 * k0, k2 * k0, k2 * k1, k3 * k0, k3 * k1, k3 * k2,
                   q1 * k0, q2 * k0, q2 * k1, q3 * k0, q3 * k1, q3 * k2};
    #pragma unroll
    for (int m = 1; m < 64; m <<= 1)
        #pragma unroll
        for (int i = 0; i < 12; ++i) s[i] += __shfl_xor(s[i], m, 64);
    __shared__ float part[2][12];
    if ((d & 63) == 0) {
        int w = d >> 6;
        #pragma unroll
        for (int i = 0; i < 12; ++i) part[w][i] = s[i];
    }
    __syncthreads();
    if (d < 12) {
        float v = part[0][d] + part[1][d];
        pcx[((size_t)(2 * hkv)     * 512 + g) * 12 + d] = v;
        pcx[((size_t)(2 * hkv + 1) * 512 + g) * 12 + d] = v;
    }
}

// ---------- conv+silu for v ----------
__global__ __launch_bounds__(256) void conv_v_kernel(
    const bf16* __restrict__ mixed, const float* __restrict__ cv, bf16* __restrict__ vv)
{
    int idx = blockIdx.x * 256 + threadIdx.x;
    int t = idx >> 12, c = idx & 4095;
    float acc = 0.f;
    #pragma unroll
    for (int j = 0; j < 4; ++j) {
        int ts = t - 3 + j;
        if (ts >= 0)
            acc += __bfloat162float(mixed[(size_t)ts * 8192 + 4096 + c]) * cv[c * 4 + j];
    }
    vv[idx] = __float2bfloat16(acc / (1.f + __expf(-acc)));
}

// ---------- gating: pack pk4[h][t][{e^g, -beta*e^g, beta, (qk)}] -------------
// word 3 (qk) is written by conv_qk_kernel — do NOT touch it here.
__global__ __launch_bounds__(256) void gating_kernel(
    const float* __restrict__ ab, const float* __restrict__ dt_bias,
    const float* __restrict__ A_log, float* __restrict__ pk4)
{
    int i = blockIdx.x * 256 + threadIdx.x;
    int h = i >> 11, t = i & 2047;
    float a  = ab[(size_t)t * 128 + h] + dt_bias[h];
    float sp = (a <= 20.f) ? log1pf(__expf(a)) : a;
    float gg = -__expf(A_log[h]) * sp;
    float b  = ab[(size_t)t * 128 + 32 + h];
    float eg = __expf(gg);
    float be = 1.f / (1.f + __expf(-b));
    size_t base = ((size_t)h * T_TOK + t) * 4;
    pk4[base + 0] = eg;
    pk4[base + 1] = -be * eg;
    pk4[base + 2] = be;
}

// ---------- gated delta-rule recurrence (v10: 4-token lookahead) ------------
// v9 forensics: 844cy/pair = 342 issue + ~500 stall PER TRAVERSAL. v10
// amortizes the traversal over 4 tokens: all 8 dots (k0..k3,q0..q3) run off
// S0 concurrently -> ONE red16x8; scalar ladder dvv0->dvv1->dvv2->dvv3 via
// precomputed within-group cross terms (xterm); S-update is a rank-4 pkfma
// chain S = eall*S + c0*k0 + c1*k1 + c2*k2 + c3*k3 (5 ops/reg — cheaper per
// token than sequential). Discriminates traversal-latency (expect ~230-280us)
// vs LDS-pipe-bound (~null; next lever = bf16 k/q in LDS).
#define TILE 16

__global__ __launch_bounds__(256, 1) void recur_kernel(
    const float* __restrict__ qn, const float* __restrict__ kn, const bf16* __restrict__ vv,
    const float* __restrict__ pk4, const float* __restrict__ pcx, bf16* __restrict__ o)
{
    __shared__ float    skq[2][TILE][256];   // [buf][tok][k0..127|q0..127] = 32 KB
    __shared__ float    sgt[2][TILE][4];     // [buf][tok][eg,-b*eg,b,qk]   = 512 B
    __shared__ float    sgx[2][48];          // [buf][4 groups][12 cross]   = 384 B
    __shared__ uint16_t sv2[2][TILE][16];    // [buf][tok][16 dv bf16]      = 1 KB

    int h    = blockIdx.x;          // 0..31
    int sp   = blockIdx.y;          // 0..7
    int tid  = threadIdx.x;
    int dvl  = tid >> 4;            // 0..15
    int dkg  = tid & 15;            // 0..15
    int dv   = sp * 16 + dvl;
    int hkv  = h >> 1;              // GQA repeat-interleave
    int wave = tid >> 6;            // 0..3
    int lane = tid & 63;
    bool writer = (dkg == 0);

    bf16* optr = o + (size_t)h * DVh + dv;

    // per-lane global source for k/q staging (lane<32 -> k, lane>=32 -> q)
    const float* kqsrc = (lane < 32)
        ? (kn + (size_t)hkv * DKh + (size_t)lane * 4)
        : (qn + (size_t)hkv * DKh + (size_t)(lane - 32) * 4);
    const bf16*  vsrc  = vv + (size_t)h * DVh + sp * 16 + (size_t)(lane & 1) * 8;
    const float* gsrc  = pk4 + ((size_t)h * T_TOK) * 4;
    const float* xsrc  = pcx + (size_t)h * 512 * 12;

    f32x2 S[4] = {};

    // stage tile [t0, t0+TILE) into buffer b. OOB reads on the final prefetch
    // land in adjacent live workspace allocations / pad; values unused.
    auto stage = [&](int b, int t0) {
        #pragma unroll
        for (int i = 0; i < 4; ++i) {
            int tok = wave * 4 + i;
            gload16(kqsrc + (size_t)(t0 + tok) * 2048, (void*)&skq[b][tok][0]);
        }
        if (wave == 0) {
            if (lane < 32)
                gload16(vsrc + (size_t)(t0 + (lane >> 1)) * 4096, (void*)&sv2[b][0][0]);
        } else if (wave == 1) {
            if (lane < 16)
                gload16(gsrc + (size_t)(t0 + lane) * 4, (void*)&sgt[b][0][0]);
        } else if (wave == 2) {
            if (lane < 12)
                gload16(xsrc + (size_t)(t0 >> 2) * 12 + (size_t)lane * 4, (void*)&sgx[b][0]);
        }
    };

    stage(0, 0);
    __syncthreads();                 // drains vmcnt -> tile 0 visible

    int buf = 0;
    #pragma unroll 1
    for (int t0 = 0; t0 < T_TOK; t0 += TILE) {
        stage(buf ^ 1, t0 + TILE);   // async prefetch next tile (no VGPR cost)
        #pragma unroll
        for (int gi = 0; gi < 4; ++gi) {
            int s0 = gi * 4;
            // ---- load group operands from LDS ----
            f32x2 kv[4][4], qv[4][4];
            #pragma unroll
            for (int tt = 0; tt < 4; ++tt) {
                const float* tp = &skq[buf][s0 + tt][0];
                float4 a = *(const float4*)(tp + dkg * 4);
                float4 b = *(const float4*)(tp + 64 + dkg * 4);
                float4 c = *(const float4*)(tp + 128 + dkg * 4);
                float4 d = *(const float4*)(tp + 192 + dkg * 4);
                kv[tt][0] = {a.x, a.y}; kv[tt][1] = {a.z, a.w};
                kv[tt][2] = {b.x, b.y}; kv[tt][3] = {b.z, b.w};
                qv[tt][0] = {c.x, c.y}; qv[tt][1] = {c.z, c.w};
                qv[tt][2] = {d.x, d.y}; qv[tt][3] = {d.z, d.w};
            }
            float4 g0 = *(const float4*)(&sgt[buf][s0 + 0][0]);
            float4 g1 = *(const float4*)(&sgt[buf][s0 + 1][0]);
            float4 g2 = *(const float4*)(&sgt[buf][s0 + 2][0]);
            float4 g3 = *(const float4*)(&sgt[buf][s0 + 3][0]);
            const float* cxp = &sgx[buf][gi * 12];
            float4 cxA = *(const float4*)(cxp);        // kk10,kk20,kk21,kk30
            float4 cxB = *(const float4*)(cxp + 4);    // kk31,kk32,qk10,qk20
            float4 cxC = *(const float4*)(cxp + 8);    // qk21,qk30,qk31,qk32
            float v0 = __uint_as_float((uint32_t)sv2[buf][s0 + 0][dvl] << 16);
            float v1 = __uint_as_float((uint32_t)sv2[buf][s0 + 1][dvl] << 16);
            float v2 = __uint_as_float((uint32_t)sv2[buf][s0 + 2][dvl] << 16);
            float v3 = __uint_as_float((uint32_t)sv2[buf][s0 + 3][dvl] << 16);

            // ---- 8 dots off S0 (full ILP) ----
            f32x2 pK0 = pkfma(S[3], kv[0][3], S[2] * kv[0][2]) + pkfma(S[1], kv[0][1], S[0] * kv[0][0]);
            f32x2 pQ0 = pkfma(S[3], qv[0][3], S[2] * qv[0][2]) + pkfma(S[1], qv[0][1], S[0] * qv[0][0]);
            f32x2 pK1 = pkfma(S[3], kv[1][3], S[2] * kv[1][2]) + pkfma(S[1], kv[1][1], S[0] * kv[1][0]);
            f32x2 pQ1 = pkfma(S[3], qv[1][3], S[2] * qv[1][2]) + pkfma(S[1], qv[1][1], S[0] * qv[1][0]);
            f32x2 pK2 = pkfma(S[3], kv[2][3], S[2] * kv[2][2]) + pkfma(S[1], kv[2][1], S[0] * kv[2][0]);
            f32x2 pQ2 = pkfma(S[3], qv[2][3], S[2] * qv[2][2]) + pkfma(S[1], qv[2][1], S[0] * qv[2][0]);
            f32x2 pK3 = pkfma(S[3], kv[3][3], S[2] * kv[3][2]) + pkfma(S[1], kv[3][1], S[0] * kv[3][0]);
            f32x2 pQ3 = pkfma(S[3], qv[3][3], S[2] * qv[3][2]) + pkfma(S[1], qv[3][1], S[0] * qv[3][0]);
            float K0 = pK0.x + pK0.y, Q0 = pQ0.x + pQ0.y;
            float K1 = pK1.x + pK1.y, Q1 = pQ1.x + pQ1.y;
            float K2 = pK2.x + pK2.y, Q2 = pQ2.x + pQ2.y;
            float K3 = pK3.x + pK3.y, Q3 = pQ3.x + pQ3.y;
            red16x8(K0, Q0, K1, Q1, K2, Q2, K3, Q3);

            // ---- scalar ladder (short serial chain) ----
            float e0 = g0.x, e1 = g1.x, e2 = g2.x, e3 = g3.x;
            float e01 = e0 * e1, e12 = e1 * e2, e012 = e01 * e2;
            float bv0 = g0.z * v0, bv1 = g1.z * v1, bv2 = g2.z * v2, bv3 = g3.z * v3;
            float dvv0 = fmaf(g0.y, K0, bv0);
            float d1   = fmaf(cxA.x, dvv0, e0 * K1);
            float dvv1 = fmaf(g1.y, d1, bv1);
            float d2p  = fmaf(e1 * cxA.y, dvv0, e01 * K2);
            float d2   = fmaf(cxA.z, dvv1, d2p);
            float dvv2 = fmaf(g2.y, d2, bv2);
            float d3p  = fmaf(e12 * cxA.w, dvv0, e012 * K3);
            d3p        = fmaf(e2 * cxB.x, dvv1, d3p);
            float d3   = fmaf(cxB.y, dvv2, d3p);
            float dvv3 = fmaf(g3.y, d3, bv3);

            // ---- S update: rank-4 + decay ----
            float e23 = e2 * e3, e123 = e1 * e23, eall = e0 * e123;
            f32x2 ev = sp2(eall);
            f32x2 c0 = sp2(e123 * dvv0), c1 = sp2(e23 * dvv1);
            f32x2 c2 = sp2(e3 * dvv2),   c3 = sp2(dvv3);
            #pragma unroll
            for (int j = 0; j < 4; ++j)
                S[j] = pkfma(kv[3][j], c3, pkfma(kv[2][j], c2,
                       pkfma(kv[1][j], c1, pkfma(kv[0][j], c0, S[j] * ev))));

            // ---- outputs (off-chain) ----
            if (writer) {
                float o0  = fmaf(g0.w, dvv0, e0 * Q0);
                float q1p = fmaf(cxB.z, dvv0, e0 * Q1);
                float o1  = fmaf(g1.w, dvv1, e1 * q1p);
                float q2p = fmaf(e1 * cxB.w, dvv0, e01 * Q2);
                q2p       = fmaf(cxC.x, dvv1, q2p);
                float o2  = fmaf(g2.w, dvv2, e2 * q2p);
                float q3p = fmaf(e12 * cxC.y, dvv0, e012 * Q3);
                q3p       = fmaf(e2 * cxC.z, dvv1, q3p);
                q3p       = fmaf(cxC.w, dvv2, q3p);
                float o3  = fmaf(g3.w, dvv3, e3 * q3p);
                optr[(size_t)(t0 + s0 + 0) * 4096] = __float2bfloat16(o0);
                optr[(size_t)(t0 + s0 + 1) * 4096] = __float2bfloat16(o1);
                optr[(size_t)(t0 + s0 + 2) * 4096] = __float2bfloat16(o2);
                optr[(size_t)(t0 + s0 + 3) * 4096] = __float2bfloat16(o3);
            }
        }
        __syncthreads();             // all waves done reading + next tile landed
        buf ^= 1;
    }
}

// ---------- gated RMSNorm ----------
__global__ __launch_bounds__(256) void normgate_kernel(
    const bf16* __restrict__ o, const bf16* __restrict__ gate,
    const float* __restrict__ w, bf16* __restrict__ og)
{
    int grp  = blockIdx.x * 4 + (threadIdx.x >> 6);
    int lane = threadIdx.x & 63;
    int t = grp >> 5, h = grp & 31;
    size_t base = (size_t)t * 4096 + h * DVh;
    uint32_t uo = *(const uint32_t*)(o + base + lane * 2);
    float a, b; bf2f(uo, a, b);
    float ss = a * a + b * b;
    #pragma unroll
    for (int m = 1; m < 64; m <<= 1) ss += __shfl_xor(ss, m, 64);
    float rn = rsqrtf(ss * (1.f / 128.f) + 1e-5f);
    uint32_t ug = *(const uint32_t*)(gate + base + lane * 2);
    float ga, gb; bf2f(ug, ga, gb);
    float wa = w[lane * 2], wb = w[lane * 2 + 1];
    float oa = a * rn * wa * (ga / (1.f + __expf(-ga)));
    float ob = b * rn * wb * (gb / (1.f + __expf(-gb)));
    og[base + lane * 2]     = __float2bfloat16(oa);
    og[base + lane * 2 + 1] = __float2bfloat16(ob);
}

// ---------- launch ----------
extern "C" void kernel_launch(void* const* d_in, const int* in_sizes, int n_in,
                              void* d_out, int out_size, void* d_ws, size_t ws_size,
                              hipStream_t stream)
{
    const float* h       = (const float*)d_in[0];
    const float* Wq      = (const float*)d_in[1];
    const float* Wk      = (const float*)d_in[2];
    const float* Wv      = (const float*)d_in[3];
    const float* Wa      = (const float*)d_in[4];
    const float* Wb      = (const float*)d_in[5];
    const float* Wg      = (const float*)d_in[6];
    const float* conv_q  = (const float*)d_in[7];
    const float* conv_k  = (const float*)d_in[8];
    const float* conv_v  = (const float*)d_in[9];
    const float* dt_bias = (const float*)d_in[10];
    const float* A_log   = (const float*)d_in[11];
    const float* onw     = (const float*)d_in[12];
    const float* Wo      = (const float*)d_in[13];
    float* out = (float*)d_out;

    char* ws = (char*)d_ws;
    bf16*  WqkvT = (bf16*)ws;   ws += (size_t)8192 * 2048 * 2;   // 33.5 MB
    bf16*  WgT   = (bf16*)ws;   ws += (size_t)4096 * 2048 * 2;   // 16.8 MB (reused as qnb)
    bf16*  WoT   = (bf16*)ws;   ws += (size_t)2048 * 4096 * 2;   // 16.8 MB
    bf16*  WabT  = (bf16*)ws;   ws += (size_t)128 * 2048 * 2;
    bf16*  hb    = (bf16*)ws;   ws += (size_t)2048 * 2048 * 2;
    bf16*  mixed = (bf16*)ws;   ws += (size_t)2048 * 8192 * 2;   // 33.5 MB
    float* ab    = (float*)ws;  ws += (size_t)2048 * 128 * 4;
    float* knb   = (float*)ws;  ws += (size_t)2048 * 2048 * 4;   // 16.8 MB fp32
    bf16*  vvb   = (bf16*)ws;   ws += (size_t)2048 * 4096 * 2;   // 16.8 MB
    float* pk4   = (float*)ws;  ws += (size_t)NH * T_TOK * 4 * 4; // [h][t][{eg,-b*eg,b,qk}]
    float* pcx   = (float*)ws;  ws += (size_t)NH * 512 * 12 * 4;  // [h][g][12 cross terms]
    ws += 32768;                                                 // OOB-prefetch pad
    // aliases over dead regions (stream-ordered lifetimes):
    float* qnb = (float*)WgT;                      // WgT dead after gate GEMM
    bf16*  ob   = WqkvT;                           // WqkvT dead after qkv GEMM
    bf16*  gate = WqkvT + (size_t)2048 * 4096;     // second half of WqkvT region
    bf16*  og   = mixed;                           // mixed dead after conv kernels

    dim3 tb(32, 8);
    transpose_kernel<<<dim3(64, 64),  tb, 0, stream>>>(Wq, WqkvT,                       2048, 2048);
    transpose_kernel<<<dim3(64, 64),  tb, 0, stream>>>(Wk, WqkvT + (size_t)2048 * 2048, 2048, 2048);
    transpose_kernel<<<dim3(128, 64), tb, 0, stream>>>(Wv, WqkvT + (size_t)4096 * 2048, 2048, 4096);
    transpose_kernel<<<dim3(128, 64), tb, 0, stream>>>(Wg, WgT,                         2048, 4096);
    transpose_kernel<<<dim3(64, 128), tb, 0, stream>>>(Wo, WoT,                         4096, 2048);
    build_wab_kernel<<<dim3(8, 128), 256, 0, stream>>>(Wa, Wb, WabT);
    f2b_kernel<<<16384, 256, 0, stream>>>(h, hb, 2048 * 2048);

    gemm_bt_kernel<bf16> <<<dim3(16, 64), 256, 0, stream>>>(hb, WqkvT, mixed, 2048, 8192, 2048);
    gemm_bt_kernel<float><<<dim3(16, 1),  256, 0, stream>>>(hb, WabT,  ab,    2048, 128,  2048);
    gemm_bt_kernel<bf16> <<<dim3(16, 32), 256, 0, stream>>>(hb, WgT,   gate,  2048, 4096, 2048);

    conv_qk_kernel<<<dim3(2048, 16), 128, 0, stream>>>(mixed, conv_q, conv_k, qnb, knb, pk4);
    conv_v_kernel<<<32768, 256, 0, stream>>>(mixed, conv_v, vvb);
    gating_kernel<<<256, 256, 0, stream>>>(ab, dt_bias, A_log, pk4);
    xterm_kernel<<<dim3(512, 16), 128, 0, stream>>>(qnb, knb, pcx);

    recur_kernel<<<dim3(32, 8), 256, 0, stream>>>(qnb, knb, vvb, pk4, pcx, ob);
    normgate_kernel<<<16384, 256, 0, stream>>>(ob, gate, onw, og);

    gemm_bt_kernel<float><<<dim3(16, 16), 256, 0, stream>>>(og, WoT, out, 2048, 2048, 4096);
}